// Round 11
// baseline (316.139 us; speedup 1.0000x reference)
//
#include <hip/hip_runtime.h>
#include <math.h>

#define N_NODES 100000
#define N_PART  5000
#define N_EDGES 1000000
#define D_NODE  128
#define D_PART  128
#define D_ATT   20
#define NBLK    128   // histogram blocks
#define EPB     ((N_EDGES + NBLK - 1) / NBLK)
#define TPV6    8     // particles per block in gru_fused_v6 / query path
#define QBLKS   (N_PART / TPV6)   // 625 query blocks

__device__ __forceinline__ float sigmoid_(float x) { return 1.f / (1.f + __expf(-x)); }
__device__ __forceinline__ float tanh_(float x)    { return 1.f - 2.f / (__expf(2.f * x) + 1.f); }

// 16-FMA body for the 512-wide GRU GEMM (4 k-rows x 4 cols x 4 particles)
__device__ __forceinline__ void gru_body(float4 acc[4],
    float4 w0, float4 w1, float4 w2, float4 w3,
    float4 x0, float4 x1, float4 x2, float4 x3)
{
    acc[0].x += x0.x * w0.x + x0.y * w1.x + x0.z * w2.x + x0.w * w3.x;
    acc[0].y += x0.x * w0.y + x0.y * w1.y + x0.z * w2.y + x0.w * w3.y;
    acc[0].z += x0.x * w0.z + x0.y * w1.z + x0.z * w2.z + x0.w * w3.z;
    acc[0].w += x0.x * w0.w + x0.y * w1.w + x0.z * w2.w + x0.w * w3.w;
    acc[1].x += x1.x * w0.x + x1.y * w1.x + x1.z * w2.x + x1.w * w3.x;
    acc[1].y += x1.x * w0.y + x1.y * w1.y + x1.z * w2.y + x1.w * w3.y;
    acc[1].z += x1.x * w0.z + x1.y * w1.z + x1.z * w2.z + x1.w * w3.z;
    acc[1].w += x1.x * w0.w + x1.y * w1.w + x1.z * w2.w + x1.w * w3.w;
    acc[2].x += x2.x * w0.x + x2.y * w1.x + x2.z * w2.x + x2.w * w3.x;
    acc[2].y += x2.x * w0.y + x2.y * w1.y + x2.z * w2.y + x2.w * w3.y;
    acc[2].z += x2.x * w0.z + x2.y * w1.z + x2.z * w2.z + x2.w * w3.z;
    acc[2].w += x2.x * w0.w + x2.y * w1.w + x2.z * w2.w + x2.w * w3.w;
    acc[3].x += x3.x * w0.x + x3.y * w1.x + x3.z * w2.x + x3.w * w3.x;
    acc[3].y += x3.x * w0.y + x3.y * w1.y + x3.z * w2.y + x3.w * w3.y;
    acc[3].z += x3.x * w0.z + x3.y * w1.z + x3.z * w2.z + x3.w * w3.z;
    acc[3].w += x3.x * w0.w + x3.y * w1.w + x3.z * w2.w + x3.w * w3.w;
}

// ---------------------------------------------------------------------------
// L1 — fused front-end (897 blocks). Disjoint sections (no cross-section
// reads; every input is a kernel argument):
//   [0,12):    Wcomb tiled GEMM — C[k][j] = valW[k]·Wih[j] (k<128, j<384),
//              64x64 tiles, LDS-staged, coalesced
//   [12,14):   zero-fill Wbig rows 0-127, gate g=3 (jn = 4c+3)
//   [14,142):  copy Whh into Wbig rows 128-255 (gate-interleaved).
//              *** round-10 bug fixed: 2 entries/thread -> all 65536
//              entries covered (was 32768; rows 192-255 were stale) ***
//   [142,144): bvec[c] = valb . Wih[c]  (c < 384)
//   [144,272): block_hist — LDS histogram of dst, atomicAdd into totals
//   [272,897): query two-stage rank-20 (verified round 9)
// ---------------------------------------------------------------------------
__global__ __launch_bounds__(256) void fused_front_kernel(
    const float* __restrict__ valW, const float* __restrict__ Wih,
    const float* __restrict__ Whh, float* __restrict__ Wbig,
    const float* __restrict__ valb, float* __restrict__ bvec,
    const int* __restrict__ dst, int* __restrict__ totals,
    const float* __restrict__ ph, const float* __restrict__ gr,
    const float* __restrict__ qW, const float* __restrict__ qb,
    const float* __restrict__ keyW, const float* __restrict__ keyb,
    float* __restrict__ qk, float* __restrict__ qoff)
{
    __shared__ float pool[5000];   // 20000 B unioned
    int blk = blockIdx.x;
    int t = threadIdx.x;

    if (blk < 12) {
        // ---- Wcomb tiled GEMM: C = valW(128x128) * Wih(384x128)^T ----
        float (*sA)[33] = (float (*)[33])pool;          // 64x33
        float (*sB)[33] = (float (*)[33])(pool + 2112); // 64x33
        int bk = blk / 6, bj = blk - bk * 6;
        int k0 = bk * 64, j0 = bj * 64;
        int tk = t >> 4, tj = t & 15;
        float acc[4][4];
        #pragma unroll
        for (int i = 0; i < 4; i++)
            #pragma unroll
            for (int j = 0; j < 4; j++) acc[i][j] = 0.f;

        for (int mc = 0; mc < 128; mc += 32) {
            #pragma unroll
            for (int s = 0; s < 2; s++) {
                int f = t + s * 256;          // 0..511
                int r = f >> 3, c4 = (f & 7) * 4;
                *(float4*)&sA[r][c4] = *(const float4*)(valW + (size_t)(k0 + r) * 128 + mc + c4);
                *(float4*)&sB[r][c4] = *(const float4*)(Wih  + (size_t)(j0 + r) * 128 + mc + c4);
            }
            __syncthreads();
            #pragma unroll 8
            for (int mm = 0; mm < 32; mm++) {
                float a0 = sA[tk * 4 + 0][mm], a1 = sA[tk * 4 + 1][mm];
                float a2 = sA[tk * 4 + 2][mm], a3 = sA[tk * 4 + 3][mm];
                float b0 = sB[tj * 4 + 0][mm], b1 = sB[tj * 4 + 1][mm];
                float b2 = sB[tj * 4 + 2][mm], b3 = sB[tj * 4 + 3][mm];
                acc[0][0] += a0 * b0; acc[0][1] += a0 * b1; acc[0][2] += a0 * b2; acc[0][3] += a0 * b3;
                acc[1][0] += a1 * b0; acc[1][1] += a1 * b1; acc[1][2] += a1 * b2; acc[1][3] += a1 * b3;
                acc[2][0] += a2 * b0; acc[2][1] += a2 * b1; acc[2][2] += a2 * b2; acc[2][3] += a2 * b3;
                acc[3][0] += a3 * b0; acc[3][1] += a3 * b1; acc[3][2] += a3 * b2; acc[3][3] += a3 * b3;
            }
            __syncthreads();
        }
        // write-out with gate-interleave: old j -> jn = (j&127)*4 + (j>>7)
        #pragma unroll
        for (int i = 0; i < 4; i++) {
            int k = k0 + tk * 4 + i;
            #pragma unroll
            for (int j = 0; j < 4; j++) {
                int oj = j0 + tj * 4 + j;            // < 384
                Wbig[(size_t)k * 512 + (oj & 127) * 4 + (oj >> 7)] = acc[i][j];
            }
        }
    } else if (blk < 14) {
        // ---- zero-fill rows 0-127, g=3 ----
        for (int f = t; f < 8192; f += 256) {
            int e = (blk - 12) * 8192 + f;   // 0..16383
            int k = e >> 7, c = e & 127;
            Wbig[(size_t)k * 512 + c * 4 + 3] = 0.f;
        }
    } else if (blk < 142) {
        // ---- copy Whh rows 128-255 (FIXED: 2 entries per thread) ----
        #pragma unroll
        for (int s = 0; s < 2; s++) {
            int idx = 65536 + (blk - 14) * 512 + s * 256 + t;  // 65536..131071
            int k = idx >> 9;            // 128..255
            int jn = idx & 511;
            int j = (jn & 3) * 128 + (jn >> 2);
            int kp = k - 128;
            float v = 0.f;
            if (j < 256)       v = Whh[j * 128 + kp];
            else if (j >= 384) v = Whh[(j - 128) * 128 + kp];
            Wbig[(size_t)k * 512 + jn] = v;
        }
    } else if (blk < 144) {
        // ---- bvec (verified) ----
        int c = (blk - 142) * 256 + t;
        if (c < 384) {
            float acc = 0.f;
            #pragma unroll 8
            for (int m = 0; m < 128; m++) acc += valb[m] * Wih[c * 128 + m];
            bvec[c] = acc;
        }
    } else if (blk < 272) {
        // ---- block_hist -> atomic totals ----
        int b = blk - 144;
        int* h = (int*)pool;
        for (int i = t; i < N_PART; i += 256) h[i] = 0;
        __syncthreads();
        int beg = b * EPB, end = min(beg + EPB, N_EDGES);
        for (int e = beg + t; e < end; e += 256)
            atomicAdd(&h[dst[e]], 1);
        __syncthreads();
        for (int i = t; i < N_PART; i += 256)
            if (h[i]) atomicAdd(&totals[i], h[i]);
    } else {
        // ---- query two-stage (rank-20, LDS-resident — verified round 9) ----
        float (*s_in)[260] = (float (*)[260])pool;
        float (*s_q)[20]   = (float (*)[20])(pool + 2080);
        float (*s_kw)[21]  = (float (*)[21])(pool + 2240);
        float* s_kb = pool + 4928;
        float* s_qb = pool + 4948;

        int pbase = (blk - 272) * TPV6;

        for (int f = t; f < TPV6 * 64; f += 256) {
            int pl = f >> 6, r = f & 63;
            int c4 = r * 4;
            int p = pbase + pl;
            float4 v;
            if (c4 < 128) v = *(const float4*)(ph + (size_t)p * 128 + c4);
            else          v = *(const float4*)(gr + (size_t)p * 128 + (c4 - 128));
            *(float4*)&s_in[pl][c4] = v;
        }
        for (int f = t; f < 2560; f += 256) {
            int j = f / 20, a = f - j * 20;
            s_kw[j][a] = keyW[f];
        }
        if (t < 20) { s_kb[t] = keyb[t]; s_qb[t] = qb[t]; }
        __syncthreads();

        if (t < 160) {
            int pl = t / 20, a = t - (t / 20) * 20;
            float acc = s_qb[a];
            const float* qwp = qW + a;
            #pragma unroll 8
            for (int k = 0; k < 256; k++) acc += s_in[pl][k] * qwp[k * 20];
            s_q[pl][a] = acc;
        }
        __syncthreads();

        {
            int pl = t >> 5, j0 = (t & 31) * 4;
            float acc0 = 0.f, acc1 = 0.f, acc2 = 0.f, acc3 = 0.f;
            #pragma unroll
            for (int a = 0; a < 20; a++) {
                float qv = s_q[pl][a];
                acc0 += qv * s_kw[j0][a];
                acc1 += qv * s_kw[j0 + 1][a];
                acc2 += qv * s_kw[j0 + 2][a];
                acc3 += qv * s_kw[j0 + 3][a];
            }
            float4 o; o.x = acc0; o.y = acc1; o.z = acc2; o.w = acc3;
            *(float4*)(qk + (size_t)(pbase + pl) * 128 + j0) = o;

            if (t < TPV6) {
                float acc = 0.f;
                #pragma unroll
                for (int a = 0; a < 20; a++) acc += s_kb[a] * s_q[t][a];
                qoff[pbase + t] = acc;
            }
        }
    }
}

// ---------------------------------------------------------------------------
// L2: exclusive scan of totals[5000] -> offsets[5001], plus cursor copy
// cur[i] = offsets[i] for the atomic scatter.
// ---------------------------------------------------------------------------
__global__ __launch_bounds__(256) void scan_kernel(
    const int* __restrict__ totals, int* __restrict__ offsets,
    int* __restrict__ cur)
{
    __shared__ int ss[256];
    int t = threadIdx.x;
    const int CH = 20;
    int beg = t * CH;
    int end = min(beg + CH, N_PART);
    int lsum = 0;
    for (int i = beg; i < end; i++) lsum += totals[i];
    ss[t] = lsum;
    __syncthreads();
    for (int off = 1; off < 256; off <<= 1) {
        int v = (t >= off) ? ss[t - off] : 0;
        __syncthreads();
        ss[t] += v;
        __syncthreads();
    }
    int base = ss[t] - lsum;
    for (int i = beg; i < end; i++) {
        offsets[i] = base;
        cur[i] = base;
        base += totals[i];
    }
    if (t == 0) offsets[N_PART] = N_EDGES;
}

// ---------------------------------------------------------------------------
// L3: scatter src into dst-grouped order via GLOBAL atomic cursors.
// Order within a dst segment is arbitrary — segment-sum in edge_agg is
// order-insensitive within FP tolerance.
// ---------------------------------------------------------------------------
__global__ __launch_bounds__(256) void scatter_atomic_kernel(
    const int* __restrict__ src, const int* __restrict__ dst,
    int* __restrict__ cur, int* __restrict__ ssrc)
{
    int stride = gridDim.x * 256;
    for (int e = blockIdx.x * 256 + threadIdx.x; e < N_EDGES; e += stride) {
        int d = dst[e];
        int pos = atomicAdd(&cur[d], 1);
        ssrc[pos] = src[e];
    }
}

// ---------------------------------------------------------------------------
// L4: per-dst edge accumulation. Half-wave (32 lanes x float4) per edge.
// Round-0 form (gather-service-bound; stable 72us / 3.35TB/s across rounds).
// ---------------------------------------------------------------------------
__global__ __launch_bounds__(256) void edge_agg_kernel(
    const float* __restrict__ nodes, const float* __restrict__ qk,
    const float* __restrict__ qoff,
    const int* __restrict__ offsets, const int* __restrict__ ssrc,
    float* __restrict__ agg, float* __restrict__ att_sum)
{
    const float norm = 0.22360679774997896f;  // 1/sqrt(20)
    int p = blockIdx.x;
    int tid = threadIdx.x;
    int lane = tid & 63;
    int wave = tid >> 6;
    int half = lane >> 5;
    int colq = (lane & 31) * 4;

    const float4 q = *(const float4*)(qk + (size_t)p * 128 + colq);
    float qo = qoff[p];
    int beg = offsets[p], end = offsets[p + 1];
    int n = end - beg;
    int np = (n + 1) >> 1;   // total pairs (last may be partial)
    int npfull = n >> 1;     // pairs with both edges present

    float4 a = {0.f, 0.f, 0.f, 0.f};
    float asum = 0.f;

    int pi = wave;
    for (; pi + 12 < npfull; pi += 16) {
        int e0 = beg + 2 * pi + half;
        int s0 = ssrc[e0];
        int s1 = ssrc[e0 + 8];
        int s2 = ssrc[e0 + 16];
        int s3 = ssrc[e0 + 24];
        float4 x0 = *(const float4*)(nodes + (size_t)s0 * 128 + colq);
        float4 x1 = *(const float4*)(nodes + (size_t)s1 * 128 + colq);
        float4 x2 = *(const float4*)(nodes + (size_t)s2 * 128 + colq);
        float4 x3 = *(const float4*)(nodes + (size_t)s3 * 128 + colq);
        float d0 = x0.x * q.x + x0.y * q.y + x0.z * q.z + x0.w * q.w;
        float d1 = x1.x * q.x + x1.y * q.y + x1.z * q.z + x1.w * q.w;
        float d2 = x2.x * q.x + x2.y * q.y + x2.z * q.z + x2.w * q.w;
        float d3 = x3.x * q.x + x3.y * q.y + x3.z * q.z + x3.w * q.w;
        #pragma unroll
        for (int off = 1; off <= 16; off <<= 1) {
            d0 += __shfl_xor(d0, off, 64);
            d1 += __shfl_xor(d1, off, 64);
            d2 += __shfl_xor(d2, off, 64);
            d3 += __shfl_xor(d3, off, 64);
        }
        float t0 = (d0 + qo) * norm;
        float t1 = (d1 + qo) * norm;
        float t2 = (d2 + qo) * norm;
        float t3 = (d3 + qo) * norm;
        a.x += t0 * x0.x + t1 * x1.x + t2 * x2.x + t3 * x3.x;
        a.y += t0 * x0.y + t1 * x1.y + t2 * x2.y + t3 * x3.y;
        a.z += t0 * x0.z + t1 * x1.z + t2 * x2.z + t3 * x3.z;
        a.w += t0 * x0.w + t1 * x1.w + t2 * x2.w + t3 * x3.w;
        asum += t0 + t1 + t2 + t3;
    }
    for (; pi < np; pi += 4) {
        int e0 = beg + 2 * pi;
        bool has1 = (e0 + 1 < end);
        int s0 = ssrc[e0];
        int s1 = has1 ? ssrc[e0 + 1] : s0;
        int s = half ? s1 : s0;
        float4 x = *(const float4*)(nodes + (size_t)s * 128 + colq);
        float d = x.x * q.x + x.y * q.y + x.z * q.z + x.w * q.w;
        #pragma unroll
        for (int off = 1; off <= 16; off <<= 1) d += __shfl_xor(d, off, 64);
        float att = (d + qo) * norm;
        if (half && !has1) att = 0.f;
        a.x += att * x.x; a.y += att * x.y; a.z += att * x.z; a.w += att * x.w;
        asum += att;
    }

    a.x += __shfl_xor(a.x, 32, 64);
    a.y += __shfl_xor(a.y, 32, 64);
    a.z += __shfl_xor(a.z, 32, 64);
    a.w += __shfl_xor(a.w, 32, 64);
    asum += __shfl_xor(asum, 32, 64);

    __shared__ float s_acc[4][128];
    __shared__ float s_as[4];
    if (lane < 32) {
        *(float4*)&s_acc[wave][colq] = a;
        if (lane == 0) s_as[wave] = asum;
    }
    __syncthreads();

    if (tid < 128) {
        float v = s_acc[0][tid] + s_acc[1][tid] + s_acc[2][tid] + s_acc[3][tid];
        agg[(size_t)p * 128 + tid] = v;
        if (tid == 0) att_sum[p] = s_as[0] + s_as[1] + s_as[2] + s_as[3];
    }
}

// ---------------------------------------------------------------------------
// L5: K4 v6 (round-4 measured-good config): single K=256 GEMM
// G = [agg|h] @ Wbig_interleaved (+bias/asum*bvec), gates in registers,
// LayerNorm + MLP + residual. Barrier-free K-loop, w direct from L2-resident
// global, 1-body-deep register prefetch. TPV6=8, 625 blocks.
// ---------------------------------------------------------------------------
__global__ __launch_bounds__(256) void gru_fused_v6(
    const float* __restrict__ agg, const float* __restrict__ att_sum,
    const float* __restrict__ ph,
    const float* __restrict__ Wbig, const float* __restrict__ bvec,
    const float* __restrict__ bih, const float* __restrict__ bhh,
    const float* __restrict__ lng, const float* __restrict__ lnb,
    const float* __restrict__ W1, const float* __restrict__ b1,
    const float* __restrict__ W2, const float* __restrict__ b2,
    float* __restrict__ out)
{
    __shared__ float s_in[TPV6][256];    // [agg | h] per particle (8192 B)
    __shared__ float s_ln[TPV6][128];    //                        (4096 B)
    __shared__ float s_hid[TPV6][64];    //                        (2048 B)

    int t = threadIdx.x;
    int pbase = blockIdx.x * TPV6;

    for (int f = t; f < TPV6 * 64; f += 256) {
        int pl = f >> 6, r = f & 63;
        int c4 = r * 4;
        int p = pbase + pl;
        float4 v;
        if (c4 < 128) v = *(const float4*)(agg + (size_t)p * 128 + c4);
        else          v = *(const float4*)(ph + (size_t)p * 128 + (c4 - 128));
        *(float4*)&s_in[pl][c4] = v;
    }

    int c  = t & 127;        // output column 0..127
    int j4 = c * 4;          // interleaved column base in Wbig
    int pg = t >> 7;         // particle group 0/1 -> particles pg*4 .. pg*4+3
    float4 cb, bv;
    cb.x = bih[c]       + bhh[c];        bv.x = bvec[c];        // r
    cb.y = bih[128 + c] + bhh[128 + c];  bv.y = bvec[128 + c];  // z
    cb.z = bih[256 + c];                 bv.z = bvec[256 + c];  // i_n
    cb.w = bhh[256 + c];                 bv.w = 0.f;            // h_n
    float4 acc[4];
    #pragma unroll
    for (int i = 0; i < 4; i++) {
        float as = att_sum[pbase + pg * 4 + i];
        acc[i].x = cb.x + as * bv.x;
        acc[i].y = cb.y + as * bv.y;
        acc[i].z = cb.z + as * bv.z;
        acc[i].w = cb.w + as * bv.w;
    }
    __syncthreads();

    // ---- K-loop: barrier-free, 1-body-deep prefetch
    const float* wp = Wbig + j4;
    float4 w0 = *(const float4*)(wp);
    float4 w1 = *(const float4*)(wp + 512);
    float4 w2 = *(const float4*)(wp + 1024);
    float4 w3 = *(const float4*)(wp + 1536);
    float4 x0 = *(const float4*)&s_in[pg * 4 + 0][0];
    float4 x1 = *(const float4*)&s_in[pg * 4 + 1][0];
    float4 x2 = *(const float4*)&s_in[pg * 4 + 2][0];
    float4 x3 = *(const float4*)&s_in[pg * 4 + 3][0];
    for (int k = 0; k < 256; k += 4) {
        float4 cw0 = w0, cw1 = w1, cw2 = w2, cw3 = w3;
        float4 cx0 = x0, cx1 = x1, cx2 = x2, cx3 = x3;
        if (k < 252) {
            const float* wn = wp + (size_t)(k + 4) * 512;
            w0 = *(const float4*)(wn);
            w1 = *(const float4*)(wn + 512);
            w2 = *(const float4*)(wn + 1024);
            w3 = *(const float4*)(wn + 1536);
            x0 = *(const float4*)&s_in[pg * 4 + 0][k + 4];
            x1 = *(const float4*)&s_in[pg * 4 + 1][k + 4];
            x2 = *(const float4*)&s_in[pg * 4 + 2][k + 4];
            x3 = *(const float4*)&s_in[pg * 4 + 3][k + 4];
        }
        gru_body(acc, cw0, cw1, cw2, cw3, cx0, cx1, cx2, cx3);
    }

    // ---- gates entirely in registers: hn = (1-z)*n + z*h
    #pragma unroll
    for (int i = 0; i < 4; i++) {
        int pl = pg * 4 + i;
        float r = sigmoid_(acc[i].x);
        float z = sigmoid_(acc[i].y);
        float n = tanh_(acc[i].z + r * acc[i].w);
        float h = s_in[pl][128 + c];
        s_ln[pl][c] = (1.f - z) * n + z * h;
    }
    __syncthreads();

    // ---- LayerNorm per particle
    {
        int wv = t >> 6, l = t & 63;
        for (int pl = wv; pl < TPV6; pl += 4) {
            float v0 = s_ln[pl][l * 2], v1 = s_ln[pl][l * 2 + 1];
            float sum = v0 + v1, sq = v0 * v0 + v1 * v1;
            #pragma unroll
            for (int off = 1; off <= 32; off <<= 1) {
                sum += __shfl_xor(sum, off, 64);
                sq  += __shfl_xor(sq, off, 64);
            }
            float mu = sum * (1.f / 128.f);
            float var = sq * (1.f / 128.f) - mu * mu;
            float rstd = rsqrtf(var + 1e-5f);
            s_ln[pl][l * 2]     = (v0 - mu) * rstd * lng[l * 2] + lnb[l * 2];
            s_ln[pl][l * 2 + 1] = (v1 - mu) * rstd * lng[l * 2 + 1] + lnb[l * 2 + 1];
        }
    }
    __syncthreads();

    // ---- MLP hidden (8*64 = 512 outputs)
    for (int idx = t; idx < TPV6 * 64; idx += 256) {
        int pl = idx >> 6, u = idx & 63;
        float a0 = b1[u];
        #pragma unroll 4
        for (int k = 0; k < 128; k++) a0 += s_ln[pl][k] * W1[k * 64 + u];
        s_hid[pl][u] = fmaxf(a0, 0.f);
    }
    __syncthreads();

    // ---- MLP out + residual (256 column-quads)
    for (int idx = t; idx < TPV6 * 32; idx += 256) {
        int pl = idx >> 5, qd = idx & 31;
        int c4 = qd * 4;
        float4 o = *(const float4*)(b2 + c4);
        #pragma unroll 4
        for (int u = 0; u < 64; u++) {
            float av = s_hid[pl][u];
            float4 w = *(const float4*)(W2 + u * 128 + c4);
            o.x += av * w.x; o.y += av * w.y; o.z += av * w.z; o.w += av * w.w;
        }
        float4 h4 = *(const float4*)&s_in[pl][128 + c4];
        float4 res;
        res.x = h4.x + o.x; res.y = h4.y + o.y;
        res.z = h4.z + o.z; res.w = h4.w + o.w;
        *(float4*)(out + (size_t)(pbase + pl) * 128 + c4) = res;
    }
}

// ---------------------------------------------------------------------------
extern "C" void kernel_launch(void* const* d_in, const int* in_sizes, int n_in,
                              void* d_out, int out_size, void* d_ws, size_t ws_size,
                              hipStream_t stream) {
    const float* nodes = (const float*)d_in[0];
    const float* ph    = (const float*)d_in[1];
    const float* gr    = (const float*)d_in[2];
    const int*   src   = (const int*)d_in[3];
    const int*   dst   = (const int*)d_in[4];
    const float* keyW  = (const float*)d_in[5];
    const float* keyb  = (const float*)d_in[6];
    const float* valW  = (const float*)d_in[7];
    const float* valb  = (const float*)d_in[8];
    const float* qW    = (const float*)d_in[9];
    const float* qb    = (const float*)d_in[10];
    const float* Wih   = (const float*)d_in[11];
    const float* Whh   = (const float*)d_in[12];
    const float* bih   = (const float*)d_in[13];
    const float* bhh   = (const float*)d_in[14];
    const float* lng   = (const float*)d_in[15];
    const float* lnb   = (const float*)d_in[16];
    const float* W1    = (const float*)d_in[17];
    const float* b1    = (const float*)d_in[18];
    const float* W2    = (const float*)d_in[19];
    const float* b2    = (const float*)d_in[20];
    float* out = (float*)d_out;

    // workspace layout
    float* ws_f      = (float*)d_ws;
    float* qk        = ws_f;                     // 640,000
    float* qoff      = qk + 640000;              // 5,008
    float* agg       = qoff + 5008;              // 640,000
    float* att_sum   = agg + 640000;             // 5,008
    int*   totals    = (int*)(att_sum + 5008);   // 5,008
    int*   offsets   = totals + 5008;            // 5,008
    int*   cur       = offsets + 5008;           // 5,008
    int*   ssrc      = cur + 5008;               // 1,000,000
    float* Wbig      = (float*)(ssrc + 1000000); // 131,072
    float* bvec      = Wbig + 131072;            // 512 (384 used)

    // L0: zero the atomic histogram target (stream-ordered, capture-safe).
    hipMemsetAsync(totals, 0, N_PART * sizeof(int), stream);

    // L1: fused front (Wcomb-GEMM | zero-g3 | Whh-copy | bvec | hist | query)
    fused_front_kernel<<<272 + QBLKS, 256, 0, stream>>>(
        valW, Wih, Whh, Wbig,
        valb, bvec,
        dst, totals,
        ph, gr, qW, qb, keyW, keyb, qk, qoff);

    // L2: exclusive scan (1 block) -> offsets + cursor copy.
    scan_kernel<<<1, 256, 0, stream>>>(totals, offsets, cur);

    // L3: scatter via global atomic cursors (512 blocks, grid-stride).
    scatter_atomic_kernel<<<512, 256, 0, stream>>>(src, dst, cur, ssrc);

    // L4: edge aggregation (gather-service-bound, stable 72us).
    edge_agg_kernel<<<N_PART, 256, 0, stream>>>(nodes, qk, qoff, offsets, ssrc, agg, att_sum);

    // L5: GRU + LN + MLP + residual (round-4 v6 config).
    gru_fused_v6<<<N_PART / TPV6, 256, 0, stream>>>(
        agg, att_sum, ph, Wbig, bvec, bih, bhh, lng, lnb, W1, b1, W2, b2, out);
}

// Round 12
// 283.514 us; speedup vs baseline: 1.1151x; 1.1151x over previous
//
#include <hip/hip_runtime.h>
#include <math.h>

#define N_NODES 100000
#define N_PART  5000
#define N_EDGES 1000000
#define D_NODE  128
#define D_PART  128
#define D_ATT   20
#define NBLK    128   // counting-sort blocks
#define EPB     ((N_EDGES + NBLK - 1) / NBLK)
#define TPV6    8     // particles per block in gru_fused_v6 / query path
#define QBLKS   (N_PART / TPV6)   // 625 query blocks

__device__ __forceinline__ float sigmoid_(float x) { return 1.f / (1.f + __expf(-x)); }
__device__ __forceinline__ float tanh_(float x)    { return 1.f - 2.f / (__expf(2.f * x) + 1.f); }

// 16-FMA body for the 512-wide GRU GEMM (4 k-rows x 4 cols x 4 particles)
__device__ __forceinline__ void gru_body(float4 acc[4],
    float4 w0, float4 w1, float4 w2, float4 w3,
    float4 x0, float4 x1, float4 x2, float4 x3)
{
    acc[0].x += x0.x * w0.x + x0.y * w1.x + x0.z * w2.x + x0.w * w3.x;
    acc[0].y += x0.x * w0.y + x0.y * w1.y + x0.z * w2.y + x0.w * w3.y;
    acc[0].z += x0.x * w0.z + x0.y * w1.z + x0.z * w2.z + x0.w * w3.z;
    acc[0].w += x0.x * w0.w + x0.y * w1.w + x0.z * w2.w + x0.w * w3.w;
    acc[1].x += x1.x * w0.x + x1.y * w1.x + x1.z * w2.x + x1.w * w3.x;
    acc[1].y += x1.x * w0.y + x1.y * w1.y + x1.z * w2.y + x1.w * w3.y;
    acc[1].z += x1.x * w0.z + x1.y * w1.z + x1.z * w2.z + x1.w * w3.z;
    acc[1].w += x1.x * w0.w + x1.y * w1.w + x1.z * w2.w + x1.w * w3.w;
    acc[2].x += x2.x * w0.x + x2.y * w1.x + x2.z * w2.x + x2.w * w3.x;
    acc[2].y += x2.x * w0.y + x2.y * w1.y + x2.z * w2.y + x2.w * w3.y;
    acc[2].z += x2.x * w0.z + x2.y * w1.z + x2.z * w2.z + x2.w * w3.z;
    acc[2].w += x2.x * w0.w + x2.y * w1.w + x2.z * w2.w + x2.w * w3.w;
    acc[3].x += x3.x * w0.x + x3.y * w1.x + x3.z * w2.x + x3.w * w3.x;
    acc[3].y += x3.x * w0.y + x3.y * w1.y + x3.z * w2.y + x3.w * w3.y;
    acc[3].z += x3.x * w0.z + x3.y * w1.z + x3.z * w2.z + x3.w * w3.z;
    acc[3].w += x3.x * w0.w + x3.y * w1.w + x3.z * w2.w + x3.w * w3.w;
}

// ---------------------------------------------------------------------------
// L1 — fused front-end (897 blocks). Disjoint sections:
//   [0,12):    Wcomb tiled GEMM — C[k][j] = valW[k]·Wih[j] (k<128, j<384),
//              64x64 tiles, LDS-staged, coalesced (verified round 11)
//   [12,14):   zero-fill Wbig rows 0-127, gate g=3
//   [14,142):  copy Whh into Wbig rows 128-255, 2 entries/thread (verified)
//   [142,144): bvec[c] = valb . Wih[c]  (c < 384)
//   [144,272): block_hist — LDS histogram -> blockhist (ROUND-9 form;
//              the atomic-totals variant cost +35us in contended L2 RMWs)
//   [272,897): query two-stage rank-20 (verified round 9)
// ---------------------------------------------------------------------------
__global__ __launch_bounds__(256) void fused_front_kernel(
    const float* __restrict__ valW, const float* __restrict__ Wih,
    const float* __restrict__ Whh, float* __restrict__ Wbig,
    const float* __restrict__ valb, float* __restrict__ bvec,
    const int* __restrict__ dst, int* __restrict__ blockhist,
    const float* __restrict__ ph, const float* __restrict__ gr,
    const float* __restrict__ qW, const float* __restrict__ qb,
    const float* __restrict__ keyW, const float* __restrict__ keyb,
    float* __restrict__ qk, float* __restrict__ qoff)
{
    __shared__ float pool[5000];   // 20000 B unioned
    int blk = blockIdx.x;
    int t = threadIdx.x;

    if (blk < 12) {
        // ---- Wcomb tiled GEMM: C = valW(128x128) * Wih(384x128)^T ----
        float (*sA)[33] = (float (*)[33])pool;          // 64x33
        float (*sB)[33] = (float (*)[33])(pool + 2112); // 64x33
        int bk = blk / 6, bj = blk - bk * 6;
        int k0 = bk * 64, j0 = bj * 64;
        int tk = t >> 4, tj = t & 15;
        float acc[4][4];
        #pragma unroll
        for (int i = 0; i < 4; i++)
            #pragma unroll
            for (int j = 0; j < 4; j++) acc[i][j] = 0.f;

        for (int mc = 0; mc < 128; mc += 32) {
            #pragma unroll
            for (int s = 0; s < 2; s++) {
                int f = t + s * 256;          // 0..511
                int r = f >> 3, c4 = (f & 7) * 4;
                *(float4*)&sA[r][c4] = *(const float4*)(valW + (size_t)(k0 + r) * 128 + mc + c4);
                *(float4*)&sB[r][c4] = *(const float4*)(Wih  + (size_t)(j0 + r) * 128 + mc + c4);
            }
            __syncthreads();
            #pragma unroll 8
            for (int mm = 0; mm < 32; mm++) {
                float a0 = sA[tk * 4 + 0][mm], a1 = sA[tk * 4 + 1][mm];
                float a2 = sA[tk * 4 + 2][mm], a3 = sA[tk * 4 + 3][mm];
                float b0 = sB[tj * 4 + 0][mm], b1 = sB[tj * 4 + 1][mm];
                float b2 = sB[tj * 4 + 2][mm], b3 = sB[tj * 4 + 3][mm];
                acc[0][0] += a0 * b0; acc[0][1] += a0 * b1; acc[0][2] += a0 * b2; acc[0][3] += a0 * b3;
                acc[1][0] += a1 * b0; acc[1][1] += a1 * b1; acc[1][2] += a1 * b2; acc[1][3] += a1 * b3;
                acc[2][0] += a2 * b0; acc[2][1] += a2 * b1; acc[2][2] += a2 * b2; acc[2][3] += a2 * b3;
                acc[3][0] += a3 * b0; acc[3][1] += a3 * b1; acc[3][2] += a3 * b2; acc[3][3] += a3 * b3;
            }
            __syncthreads();
        }
        // write-out with gate-interleave: old j -> jn = (j&127)*4 + (j>>7)
        #pragma unroll
        for (int i = 0; i < 4; i++) {
            int k = k0 + tk * 4 + i;
            #pragma unroll
            for (int j = 0; j < 4; j++) {
                int oj = j0 + tj * 4 + j;            // < 384
                Wbig[(size_t)k * 512 + (oj & 127) * 4 + (oj >> 7)] = acc[i][j];
            }
        }
    } else if (blk < 14) {
        // ---- zero-fill rows 0-127, g=3 ----
        for (int f = t; f < 8192; f += 256) {
            int e = (blk - 12) * 8192 + f;   // 0..16383
            int k = e >> 7, c = e & 127;
            Wbig[(size_t)k * 512 + c * 4 + 3] = 0.f;
        }
    } else if (blk < 142) {
        // ---- copy Whh rows 128-255 (2 entries per thread, verified) ----
        #pragma unroll
        for (int s = 0; s < 2; s++) {
            int idx = 65536 + (blk - 14) * 512 + s * 256 + t;  // 65536..131071
            int k = idx >> 9;            // 128..255
            int jn = idx & 511;
            int j = (jn & 3) * 128 + (jn >> 2);
            int kp = k - 128;
            float v = 0.f;
            if (j < 256)       v = Whh[j * 128 + kp];
            else if (j >= 384) v = Whh[(j - 128) * 128 + kp];
            Wbig[(size_t)k * 512 + jn] = v;
        }
    } else if (blk < 144) {
        // ---- bvec (verified) ----
        int c = (blk - 142) * 256 + t;
        if (c < 384) {
            float acc = 0.f;
            #pragma unroll 8
            for (int m = 0; m < 128; m++) acc += valb[m] * Wih[c * 128 + m];
            bvec[c] = acc;
        }
    } else if (blk < 272) {
        // ---- block_hist -> blockhist (round-9 verified form) ----
        int b = blk - 144;
        int* h = (int*)pool;
        for (int i = t; i < N_PART; i += 256) h[i] = 0;
        __syncthreads();
        int beg = b * EPB, end = min(beg + EPB, N_EDGES);
        for (int e = beg + t; e < end; e += 256)
            atomicAdd(&h[dst[e]], 1);
        __syncthreads();
        for (int i = t; i < N_PART; i += 256)
            blockhist[(size_t)b * N_PART + i] = h[i];
    } else {
        // ---- query two-stage (rank-20, LDS-resident — verified round 9) ----
        float (*s_in)[260] = (float (*)[260])pool;
        float (*s_q)[20]   = (float (*)[20])(pool + 2080);
        float (*s_kw)[21]  = (float (*)[21])(pool + 2240);
        float* s_kb = pool + 4928;
        float* s_qb = pool + 4948;

        int pbase = (blk - 272) * TPV6;

        for (int f = t; f < TPV6 * 64; f += 256) {
            int pl = f >> 6, r = f & 63;
            int c4 = r * 4;
            int p = pbase + pl;
            float4 v;
            if (c4 < 128) v = *(const float4*)(ph + (size_t)p * 128 + c4);
            else          v = *(const float4*)(gr + (size_t)p * 128 + (c4 - 128));
            *(float4*)&s_in[pl][c4] = v;
        }
        for (int f = t; f < 2560; f += 256) {
            int j = f / 20, a = f - j * 20;
            s_kw[j][a] = keyW[f];
        }
        if (t < 20) { s_kb[t] = keyb[t]; s_qb[t] = qb[t]; }
        __syncthreads();

        if (t < 160) {
            int pl = t / 20, a = t - (t / 20) * 20;
            float acc = s_qb[a];
            const float* qwp = qW + a;
            #pragma unroll 8
            for (int k = 0; k < 256; k++) acc += s_in[pl][k] * qwp[k * 20];
            s_q[pl][a] = acc;
        }
        __syncthreads();

        {
            int pl = t >> 5, j0 = (t & 31) * 4;
            float acc0 = 0.f, acc1 = 0.f, acc2 = 0.f, acc3 = 0.f;
            #pragma unroll
            for (int a = 0; a < 20; a++) {
                float qv = s_q[pl][a];
                acc0 += qv * s_kw[j0][a];
                acc1 += qv * s_kw[j0 + 1][a];
                acc2 += qv * s_kw[j0 + 2][a];
                acc3 += qv * s_kw[j0 + 3][a];
            }
            float4 o; o.x = acc0; o.y = acc1; o.z = acc2; o.w = acc3;
            *(float4*)(qk + (size_t)(pbase + pl) * 128 + j0) = o;

            if (t < TPV6) {
                float acc = 0.f;
                #pragma unroll
                for (int a = 0; a < 20; a++) acc += s_kb[a] * s_q[t][a];
                qoff[pbase + t] = acc;
            }
        }
    }
}

// ---------------------------------------------------------------------------
// L2: per-dst column scan over blocks (round-9 verified)
// ---------------------------------------------------------------------------
__global__ __launch_bounds__(256) void colscan_kernel(
    int* __restrict__ blockhist, int* __restrict__ totals)
{
    int i = blockIdx.x * 256 + threadIdx.x;
    if (i >= N_PART) return;
    int run = 0;
    for (int b = 0; b < NBLK; b++) {
        size_t idx = (size_t)b * N_PART + i;
        int v = blockhist[idx];
        blockhist[idx] = run;
        run += v;
    }
    totals[i] = run;
}

// ---------------------------------------------------------------------------
// L3: exclusive scan of totals[5000] -> offsets[5001] (round-9 verified)
// ---------------------------------------------------------------------------
__global__ __launch_bounds__(256) void scan_kernel(
    const int* __restrict__ totals, int* __restrict__ offsets)
{
    __shared__ int ss[256];
    int t = threadIdx.x;
    const int CH = 20;
    int beg = t * CH;
    int end = min(beg + CH, N_PART);
    int lsum = 0;
    for (int i = beg; i < end; i++) lsum += totals[i];
    ss[t] = lsum;
    __syncthreads();
    for (int off = 1; off < 256; off <<= 1) {
        int v = (t >= off) ? ss[t - off] : 0;
        __syncthreads();
        ss[t] += v;
        __syncthreads();
    }
    int base = ss[t] - lsum;
    for (int i = beg; i < end; i++) {
        offsets[i] = base;
        base += totals[i];
    }
    if (t == 0) offsets[N_PART] = N_EDGES;
}

// ---------------------------------------------------------------------------
// L4: scatter src into dst-sorted order using per-block LDS cursors
// (round-9 verified; LDS atomics, not contended global RMWs)
// ---------------------------------------------------------------------------
__global__ __launch_bounds__(256) void scatter_sorted_kernel(
    const int* __restrict__ src, const int* __restrict__ dst,
    const int* __restrict__ offsets, const int* __restrict__ blockhist,
    int* __restrict__ ssrc)
{
    __shared__ int cur[N_PART];
    int b = blockIdx.x;
    for (int i = threadIdx.x; i < N_PART; i += 256)
        cur[i] = offsets[i] + blockhist[(size_t)b * N_PART + i];
    __syncthreads();
    int beg = b * EPB, end = min(beg + EPB, N_EDGES);
    for (int e = beg + threadIdx.x; e < end; e += 256) {
        int d = dst[e];
        int pos = atomicAdd(&cur[d], 1);
        ssrc[pos] = src[e];
    }
}

// ---------------------------------------------------------------------------
// L5: per-dst edge accumulation. Half-wave (32 lanes x float4) per edge.
// Round-0 form (gather-service-bound; stable 72us / 3.35TB/s across rounds).
// ---------------------------------------------------------------------------
__global__ __launch_bounds__(256) void edge_agg_kernel(
    const float* __restrict__ nodes, const float* __restrict__ qk,
    const float* __restrict__ qoff,
    const int* __restrict__ offsets, const int* __restrict__ ssrc,
    float* __restrict__ agg, float* __restrict__ att_sum)
{
    const float norm = 0.22360679774997896f;  // 1/sqrt(20)
    int p = blockIdx.x;
    int tid = threadIdx.x;
    int lane = tid & 63;
    int wave = tid >> 6;
    int half = lane >> 5;
    int colq = (lane & 31) * 4;

    const float4 q = *(const float4*)(qk + (size_t)p * 128 + colq);
    float qo = qoff[p];
    int beg = offsets[p], end = offsets[p + 1];
    int n = end - beg;
    int np = (n + 1) >> 1;   // total pairs (last may be partial)
    int npfull = n >> 1;     // pairs with both edges present

    float4 a = {0.f, 0.f, 0.f, 0.f};
    float asum = 0.f;

    int pi = wave;
    for (; pi + 12 < npfull; pi += 16) {
        int e0 = beg + 2 * pi + half;
        int s0 = ssrc[e0];
        int s1 = ssrc[e0 + 8];
        int s2 = ssrc[e0 + 16];
        int s3 = ssrc[e0 + 24];
        float4 x0 = *(const float4*)(nodes + (size_t)s0 * 128 + colq);
        float4 x1 = *(const float4*)(nodes + (size_t)s1 * 128 + colq);
        float4 x2 = *(const float4*)(nodes + (size_t)s2 * 128 + colq);
        float4 x3 = *(const float4*)(nodes + (size_t)s3 * 128 + colq);
        float d0 = x0.x * q.x + x0.y * q.y + x0.z * q.z + x0.w * q.w;
        float d1 = x1.x * q.x + x1.y * q.y + x1.z * q.z + x1.w * q.w;
        float d2 = x2.x * q.x + x2.y * q.y + x2.z * q.z + x2.w * q.w;
        float d3 = x3.x * q.x + x3.y * q.y + x3.z * q.z + x3.w * q.w;
        #pragma unroll
        for (int off = 1; off <= 16; off <<= 1) {
            d0 += __shfl_xor(d0, off, 64);
            d1 += __shfl_xor(d1, off, 64);
            d2 += __shfl_xor(d2, off, 64);
            d3 += __shfl_xor(d3, off, 64);
        }
        float t0 = (d0 + qo) * norm;
        float t1 = (d1 + qo) * norm;
        float t2 = (d2 + qo) * norm;
        float t3 = (d3 + qo) * norm;
        a.x += t0 * x0.x + t1 * x1.x + t2 * x2.x + t3 * x3.x;
        a.y += t0 * x0.y + t1 * x1.y + t2 * x2.y + t3 * x3.y;
        a.z += t0 * x0.z + t1 * x1.z + t2 * x2.z + t3 * x3.z;
        a.w += t0 * x0.w + t1 * x1.w + t2 * x2.w + t3 * x3.w;
        asum += t0 + t1 + t2 + t3;
    }
    for (; pi < np; pi += 4) {
        int e0 = beg + 2 * pi;
        bool has1 = (e0 + 1 < end);
        int s0 = ssrc[e0];
        int s1 = has1 ? ssrc[e0 + 1] : s0;
        int s = half ? s1 : s0;
        float4 x = *(const float4*)(nodes + (size_t)s * 128 + colq);
        float d = x.x * q.x + x.y * q.y + x.z * q.z + x.w * q.w;
        #pragma unroll
        for (int off = 1; off <= 16; off <<= 1) d += __shfl_xor(d, off, 64);
        float att = (d + qo) * norm;
        if (half && !has1) att = 0.f;
        a.x += att * x.x; a.y += att * x.y; a.z += att * x.z; a.w += att * x.w;
        asum += att;
    }

    a.x += __shfl_xor(a.x, 32, 64);
    a.y += __shfl_xor(a.y, 32, 64);
    a.z += __shfl_xor(a.z, 32, 64);
    a.w += __shfl_xor(a.w, 32, 64);
    asum += __shfl_xor(asum, 32, 64);

    __shared__ float s_acc[4][128];
    __shared__ float s_as[4];
    if (lane < 32) {
        *(float4*)&s_acc[wave][colq] = a;
        if (lane == 0) s_as[wave] = asum;
    }
    __syncthreads();

    if (tid < 128) {
        float v = s_acc[0][tid] + s_acc[1][tid] + s_acc[2][tid] + s_acc[3][tid];
        agg[(size_t)p * 128 + tid] = v;
        if (tid == 0) att_sum[p] = s_as[0] + s_as[1] + s_as[2] + s_as[3];
    }
}

// ---------------------------------------------------------------------------
// L6: K4 v6 (round-4 measured-good config): single K=256 GEMM
// G = [agg|h] @ Wbig_interleaved (+bias/asum*bvec), gates in registers,
// LayerNorm + MLP + residual. Barrier-free K-loop, w direct from L2-resident
// global, 1-body-deep register prefetch. TPV6=8, 625 blocks.
// ---------------------------------------------------------------------------
__global__ __launch_bounds__(256) void gru_fused_v6(
    const float* __restrict__ agg, const float* __restrict__ att_sum,
    const float* __restrict__ ph,
    const float* __restrict__ Wbig, const float* __restrict__ bvec,
    const float* __restrict__ bih, const float* __restrict__ bhh,
    const float* __restrict__ lng, const float* __restrict__ lnb,
    const float* __restrict__ W1, const float* __restrict__ b1,
    const float* __restrict__ W2, const float* __restrict__ b2,
    float* __restrict__ out)
{
    __shared__ float s_in[TPV6][256];    // [agg | h] per particle (8192 B)
    __shared__ float s_ln[TPV6][128];    //                        (4096 B)
    __shared__ float s_hid[TPV6][64];    //                        (2048 B)

    int t = threadIdx.x;
    int pbase = blockIdx.x * TPV6;

    for (int f = t; f < TPV6 * 64; f += 256) {
        int pl = f >> 6, r = f & 63;
        int c4 = r * 4;
        int p = pbase + pl;
        float4 v;
        if (c4 < 128) v = *(const float4*)(agg + (size_t)p * 128 + c4);
        else          v = *(const float4*)(ph + (size_t)p * 128 + (c4 - 128));
        *(float4*)&s_in[pl][c4] = v;
    }

    int c  = t & 127;        // output column 0..127
    int j4 = c * 4;          // interleaved column base in Wbig
    int pg = t >> 7;         // particle group 0/1 -> particles pg*4 .. pg*4+3
    float4 cb, bv;
    cb.x = bih[c]       + bhh[c];        bv.x = bvec[c];        // r
    cb.y = bih[128 + c] + bhh[128 + c];  bv.y = bvec[128 + c];  // z
    cb.z = bih[256 + c];                 bv.z = bvec[256 + c];  // i_n
    cb.w = bhh[256 + c];                 bv.w = 0.f;            // h_n
    float4 acc[4];
    #pragma unroll
    for (int i = 0; i < 4; i++) {
        float as = att_sum[pbase + pg * 4 + i];
        acc[i].x = cb.x + as * bv.x;
        acc[i].y = cb.y + as * bv.y;
        acc[i].z = cb.z + as * bv.z;
        acc[i].w = cb.w + as * bv.w;
    }
    __syncthreads();

    // ---- K-loop: barrier-free, 1-body-deep prefetch
    const float* wp = Wbig + j4;
    float4 w0 = *(const float4*)(wp);
    float4 w1 = *(const float4*)(wp + 512);
    float4 w2 = *(const float4*)(wp + 1024);
    float4 w3 = *(const float4*)(wp + 1536);
    float4 x0 = *(const float4*)&s_in[pg * 4 + 0][0];
    float4 x1 = *(const float4*)&s_in[pg * 4 + 1][0];
    float4 x2 = *(const float4*)&s_in[pg * 4 + 2][0];
    float4 x3 = *(const float4*)&s_in[pg * 4 + 3][0];
    for (int k = 0; k < 256; k += 4) {
        float4 cw0 = w0, cw1 = w1, cw2 = w2, cw3 = w3;
        float4 cx0 = x0, cx1 = x1, cx2 = x2, cx3 = x3;
        if (k < 252) {
            const float* wn = wp + (size_t)(k + 4) * 512;
            w0 = *(const float4*)(wn);
            w1 = *(const float4*)(wn + 512);
            w2 = *(const float4*)(wn + 1024);
            w3 = *(const float4*)(wn + 1536);
            x0 = *(const float4*)&s_in[pg * 4 + 0][k + 4];
            x1 = *(const float4*)&s_in[pg * 4 + 1][k + 4];
            x2 = *(const float4*)&s_in[pg * 4 + 2][k + 4];
            x3 = *(const float4*)&s_in[pg * 4 + 3][k + 4];
        }
        gru_body(acc, cw0, cw1, cw2, cw3, cx0, cx1, cx2, cx3);
    }

    // ---- gates entirely in registers: hn = (1-z)*n + z*h
    #pragma unroll
    for (int i = 0; i < 4; i++) {
        int pl = pg * 4 + i;
        float r = sigmoid_(acc[i].x);
        float z = sigmoid_(acc[i].y);
        float n = tanh_(acc[i].z + r * acc[i].w);
        float h = s_in[pl][128 + c];
        s_ln[pl][c] = (1.f - z) * n + z * h;
    }
    __syncthreads();

    // ---- LayerNorm per particle
    {
        int wv = t >> 6, l = t & 63;
        for (int pl = wv; pl < TPV6; pl += 4) {
            float v0 = s_ln[pl][l * 2], v1 = s_ln[pl][l * 2 + 1];
            float sum = v0 + v1, sq = v0 * v0 + v1 * v1;
            #pragma unroll
            for (int off = 1; off <= 32; off <<= 1) {
                sum += __shfl_xor(sum, off, 64);
                sq  += __shfl_xor(sq, off, 64);
            }
            float mu = sum * (1.f / 128.f);
            float var = sq * (1.f / 128.f) - mu * mu;
            float rstd = rsqrtf(var + 1e-5f);
            s_ln[pl][l * 2]     = (v0 - mu) * rstd * lng[l * 2] + lnb[l * 2];
            s_ln[pl][l * 2 + 1] = (v1 - mu) * rstd * lng[l * 2 + 1] + lnb[l * 2 + 1];
        }
    }
    __syncthreads();

    // ---- MLP hidden (8*64 = 512 outputs)
    for (int idx = t; idx < TPV6 * 64; idx += 256) {
        int pl = idx >> 6, u = idx & 63;
        float a0 = b1[u];
        #pragma unroll 4
        for (int k = 0; k < 128; k++) a0 += s_ln[pl][k] * W1[k * 64 + u];
        s_hid[pl][u] = fmaxf(a0, 0.f);
    }
    __syncthreads();

    // ---- MLP out + residual (256 column-quads)
    for (int idx = t; idx < TPV6 * 32; idx += 256) {
        int pl = idx >> 5, qd = idx & 31;
        int c4 = qd * 4;
        float4 o = *(const float4*)(b2 + c4);
        #pragma unroll 4
        for (int u = 0; u < 64; u++) {
            float av = s_hid[pl][u];
            float4 w = *(const float4*)(W2 + u * 128 + c4);
            o.x += av * w.x; o.y += av * w.y; o.z += av * w.z; o.w += av * w.w;
        }
        float4 h4 = *(const float4*)&s_in[pl][128 + c4];
        float4 res;
        res.x = h4.x + o.x; res.y = h4.y + o.y;
        res.z = h4.z + o.z; res.w = h4.w + o.w;
        *(float4*)(out + (size_t)(pbase + pl) * 128 + c4) = res;
    }
}

// ---------------------------------------------------------------------------
extern "C" void kernel_launch(void* const* d_in, const int* in_sizes, int n_in,
                              void* d_out, int out_size, void* d_ws, size_t ws_size,
                              hipStream_t stream) {
    const float* nodes = (const float*)d_in[0];
    const float* ph    = (const float*)d_in[1];
    const float* gr    = (const float*)d_in[2];
    const int*   src   = (const int*)d_in[3];
    const int*   dst   = (const int*)d_in[4];
    const float* keyW  = (const float*)d_in[5];
    const float* keyb  = (const float*)d_in[6];
    const float* valW  = (const float*)d_in[7];
    const float* valb  = (const float*)d_in[8];
    const float* qW    = (const float*)d_in[9];
    const float* qb    = (const float*)d_in[10];
    const float* Wih   = (const float*)d_in[11];
    const float* Whh   = (const float*)d_in[12];
    const float* bih   = (const float*)d_in[13];
    const float* bhh   = (const float*)d_in[14];
    const float* lng   = (const float*)d_in[15];
    const float* lnb   = (const float*)d_in[16];
    const float* W1    = (const float*)d_in[17];
    const float* b1    = (const float*)d_in[18];
    const float* W2    = (const float*)d_in[19];
    const float* b2    = (const float*)d_in[20];
    float* out = (float*)d_out;

    // workspace layout
    float* ws_f      = (float*)d_ws;
    float* qk        = ws_f;                     // 640,000
    float* qoff      = qk + 640000;              // 5,008
    float* agg       = qoff + 5008;              // 640,000
    float* att_sum   = agg + 640000;             // 5,008
    int*   totals    = (int*)(att_sum + 5008);   // 5,008
    int*   offsets   = totals + 5008;            // 5,008
    int*   blockhist = offsets + 5008;           // NBLK*5000
    int*   ssrc      = blockhist + (size_t)NBLK * N_PART;  // 1,000,000
    float* Wbig      = (float*)(ssrc + 1000000); // 131,072
    float* bvec      = Wbig + 131072;            // 512 (384 used)

    // L1: fused front (Wcomb-GEMM | zero-g3 | Whh-copy | bvec | hist | query)
    fused_front_kernel<<<272 + QBLKS, 256, 0, stream>>>(
        valW, Wih, Whh, Wbig,
        valb, bvec,
        dst, blockhist,
        ph, gr, qW, qb, keyW, keyb, qk, qoff);

    // L2: colscan (20 blocks).
    colscan_kernel<<<(N_PART + 255) / 256, 256, 0, stream>>>(blockhist, totals);

    // L3: exclusive scan (1 block).
    scan_kernel<<<1, 256, 0, stream>>>(totals, offsets);

    // L4: scatter with per-block LDS cursors (128 blocks).
    scatter_sorted_kernel<<<NBLK, 256, 0, stream>>>(src, dst, offsets, blockhist, ssrc);

    // L5: edge aggregation (gather-service-bound, stable 72us).
    edge_agg_kernel<<<N_PART, 256, 0, stream>>>(nodes, qk, qoff, offsets, ssrc, agg, att_sum);

    // L6: GRU + LN + MLP + residual (round-4 v6 config).
    gru_fused_v6<<<N_PART / TPV6, 256, 0, stream>>>(
        agg, att_sum, ph, Wbig, bvec, bih, bhh, lng, lnb, W1, b1, W2, b2, out);
}

// Round 13
// 275.793 us; speedup vs baseline: 1.1463x; 1.0280x over previous
//
#include <hip/hip_runtime.h>
#include <math.h>

#define N_NODES 100000
#define N_PART  5000
#define N_EDGES 1000000
#define D_NODE  128
#define D_PART  128
#define D_ATT   20
#define NBLK    128   // counting-sort blocks
#define EPB     ((N_EDGES + NBLK - 1) / NBLK)
#define TPV6    8     // particles per block in gru_fused_v6 / query path
#define QBLKS   (N_PART / TPV6)   // 625 query blocks
#define CVTBLKS 1024  // nodes->bf16 conversion blocks

__device__ __forceinline__ float sigmoid_(float x) { return 1.f / (1.f + __expf(-x)); }
__device__ __forceinline__ float tanh_(float x)    { return 1.f - 2.f / (__expf(2.f * x) + 1.f); }

// 4 bf16 (packed in uint2) -> float4
__device__ __forceinline__ float4 bf4_to_f4(uint2 r) {
    float4 f;
    f.x = __uint_as_float(r.x << 16);
    f.y = __uint_as_float(r.x & 0xFFFF0000u);
    f.z = __uint_as_float(r.y << 16);
    f.w = __uint_as_float(r.y & 0xFFFF0000u);
    return f;
}

// 16-FMA body for the 512-wide GRU GEMM (4 k-rows x 4 cols x 4 particles)
__device__ __forceinline__ void gru_body(float4 acc[4],
    float4 w0, float4 w1, float4 w2, float4 w3,
    float4 x0, float4 x1, float4 x2, float4 x3)
{
    acc[0].x += x0.x * w0.x + x0.y * w1.x + x0.z * w2.x + x0.w * w3.x;
    acc[0].y += x0.x * w0.y + x0.y * w1.y + x0.z * w2.y + x0.w * w3.y;
    acc[0].z += x0.x * w0.z + x0.y * w1.z + x0.z * w2.z + x0.w * w3.z;
    acc[0].w += x0.x * w0.w + x0.y * w1.w + x0.z * w2.w + x0.w * w3.w;
    acc[1].x += x1.x * w0.x + x1.y * w1.x + x1.z * w2.x + x1.w * w3.x;
    acc[1].y += x1.x * w0.y + x1.y * w1.y + x1.z * w2.y + x1.w * w3.y;
    acc[1].z += x1.x * w0.z + x1.y * w1.z + x1.z * w2.z + x1.w * w3.z;
    acc[1].w += x1.x * w0.w + x1.y * w1.w + x1.z * w2.w + x1.w * w3.w;
    acc[2].x += x2.x * w0.x + x2.y * w1.x + x2.z * w2.x + x2.w * w3.x;
    acc[2].y += x2.x * w0.y + x2.y * w1.y + x2.z * w2.y + x2.w * w3.y;
    acc[2].z += x2.x * w0.z + x2.y * w1.z + x2.z * w2.z + x2.w * w3.z;
    acc[2].w += x2.x * w0.w + x2.y * w1.w + x2.z * w2.w + x2.w * w3.w;
    acc[3].x += x3.x * w0.x + x3.y * w1.x + x3.z * w2.x + x3.w * w3.x;
    acc[3].y += x3.x * w0.y + x3.y * w1.y + x3.z * w2.y + x3.w * w3.y;
    acc[3].z += x3.x * w0.z + x3.y * w1.z + x3.z * w2.z + x3.w * w3.z;
    acc[3].w += x3.x * w0.w + x3.y * w1.w + x3.z * w2.w + x3.w * w3.w;
}

// ---------------------------------------------------------------------------
// L1 — fused front-end (897 or 1921 blocks). Disjoint sections:
//   [0,12):    Wcomb tiled GEMM (verified round 11/12)
//   [12,14):   zero-fill Wbig rows 0-127, gate g=3
//   [14,142):  copy Whh into Wbig rows 128-255, 2 entries/thread (verified)
//   [142,144): bvec
//   [144,272): block_hist -> blockhist (round-9/12 verified form)
//   [272,897): query two-stage rank-20 (verified round 9/12)
//   [897,1921): nodes fp32 -> bf16 (RNE), only when workspace permits —
//              halves edge_agg's random-gather bytes AND line requests.
// ---------------------------------------------------------------------------
__global__ __launch_bounds__(256) void fused_front_kernel(
    const float* __restrict__ valW, const float* __restrict__ Wih,
    const float* __restrict__ Whh, float* __restrict__ Wbig,
    const float* __restrict__ valb, float* __restrict__ bvec,
    const int* __restrict__ dst, int* __restrict__ blockhist,
    const float* __restrict__ ph, const float* __restrict__ gr,
    const float* __restrict__ qW, const float* __restrict__ qb,
    const float* __restrict__ keyW, const float* __restrict__ keyb,
    float* __restrict__ qk, float* __restrict__ qoff,
    const float* __restrict__ nodes, unsigned short* __restrict__ nodes_bf)
{
    __shared__ float pool[5000];   // 20000 B unioned
    int blk = blockIdx.x;
    int t = threadIdx.x;

    if (blk < 12) {
        // ---- Wcomb tiled GEMM: C = valW(128x128) * Wih(384x128)^T ----
        float (*sA)[33] = (float (*)[33])pool;          // 64x33
        float (*sB)[33] = (float (*)[33])(pool + 2112); // 64x33
        int bk = blk / 6, bj = blk - bk * 6;
        int k0 = bk * 64, j0 = bj * 64;
        int tk = t >> 4, tj = t & 15;
        float acc[4][4];
        #pragma unroll
        for (int i = 0; i < 4; i++)
            #pragma unroll
            for (int j = 0; j < 4; j++) acc[i][j] = 0.f;

        for (int mc = 0; mc < 128; mc += 32) {
            #pragma unroll
            for (int s = 0; s < 2; s++) {
                int f = t + s * 256;          // 0..511
                int r = f >> 3, c4 = (f & 7) * 4;
                *(float4*)&sA[r][c4] = *(const float4*)(valW + (size_t)(k0 + r) * 128 + mc + c4);
                *(float4*)&sB[r][c4] = *(const float4*)(Wih  + (size_t)(j0 + r) * 128 + mc + c4);
            }
            __syncthreads();
            #pragma unroll 8
            for (int mm = 0; mm < 32; mm++) {
                float a0 = sA[tk * 4 + 0][mm], a1 = sA[tk * 4 + 1][mm];
                float a2 = sA[tk * 4 + 2][mm], a3 = sA[tk * 4 + 3][mm];
                float b0 = sB[tj * 4 + 0][mm], b1 = sB[tj * 4 + 1][mm];
                float b2 = sB[tj * 4 + 2][mm], b3 = sB[tj * 4 + 3][mm];
                acc[0][0] += a0 * b0; acc[0][1] += a0 * b1; acc[0][2] += a0 * b2; acc[0][3] += a0 * b3;
                acc[1][0] += a1 * b0; acc[1][1] += a1 * b1; acc[1][2] += a1 * b2; acc[1][3] += a1 * b3;
                acc[2][0] += a2 * b0; acc[2][1] += a2 * b1; acc[2][2] += a2 * b2; acc[2][3] += a2 * b3;
                acc[3][0] += a3 * b0; acc[3][1] += a3 * b1; acc[3][2] += a3 * b2; acc[3][3] += a3 * b3;
            }
            __syncthreads();
        }
        #pragma unroll
        for (int i = 0; i < 4; i++) {
            int k = k0 + tk * 4 + i;
            #pragma unroll
            for (int j = 0; j < 4; j++) {
                int oj = j0 + tj * 4 + j;            // < 384
                Wbig[(size_t)k * 512 + (oj & 127) * 4 + (oj >> 7)] = acc[i][j];
            }
        }
    } else if (blk < 14) {
        // ---- zero-fill rows 0-127, g=3 ----
        for (int f = t; f < 8192; f += 256) {
            int e = (blk - 12) * 8192 + f;   // 0..16383
            int k = e >> 7, c = e & 127;
            Wbig[(size_t)k * 512 + c * 4 + 3] = 0.f;
        }
    } else if (blk < 142) {
        // ---- copy Whh rows 128-255 (2 entries per thread, verified) ----
        #pragma unroll
        for (int s = 0; s < 2; s++) {
            int idx = 65536 + (blk - 14) * 512 + s * 256 + t;  // 65536..131071
            int k = idx >> 9;            // 128..255
            int jn = idx & 511;
            int j = (jn & 3) * 128 + (jn >> 2);
            int kp = k - 128;
            float v = 0.f;
            if (j < 256)       v = Whh[j * 128 + kp];
            else if (j >= 384) v = Whh[(j - 128) * 128 + kp];
            Wbig[(size_t)k * 512 + jn] = v;
        }
    } else if (blk < 144) {
        // ---- bvec (verified) ----
        int c = (blk - 142) * 256 + t;
        if (c < 384) {
            float acc = 0.f;
            #pragma unroll 8
            for (int m = 0; m < 128; m++) acc += valb[m] * Wih[c * 128 + m];
            bvec[c] = acc;
        }
    } else if (blk < 272) {
        // ---- block_hist -> blockhist (round-9/12 verified form) ----
        int b = blk - 144;
        int* h = (int*)pool;
        for (int i = t; i < N_PART; i += 256) h[i] = 0;
        __syncthreads();
        int beg = b * EPB, end = min(beg + EPB, N_EDGES);
        for (int e = beg + t; e < end; e += 256)
            atomicAdd(&h[dst[e]], 1);
        __syncthreads();
        for (int i = t; i < N_PART; i += 256)
            blockhist[(size_t)b * N_PART + i] = h[i];
    } else if (blk < 897) {
        // ---- query two-stage (rank-20, LDS-resident — verified round 9) ----
        float (*s_in)[260] = (float (*)[260])pool;
        float (*s_q)[20]   = (float (*)[20])(pool + 2080);
        float (*s_kw)[21]  = (float (*)[21])(pool + 2240);
        float* s_kb = pool + 4928;
        float* s_qb = pool + 4948;

        int pbase = (blk - 272) * TPV6;

        for (int f = t; f < TPV6 * 64; f += 256) {
            int pl = f >> 6, r = f & 63;
            int c4 = r * 4;
            int p = pbase + pl;
            float4 v;
            if (c4 < 128) v = *(const float4*)(ph + (size_t)p * 128 + c4);
            else          v = *(const float4*)(gr + (size_t)p * 128 + (c4 - 128));
            *(float4*)&s_in[pl][c4] = v;
        }
        for (int f = t; f < 2560; f += 256) {
            int j = f / 20, a = f - j * 20;
            s_kw[j][a] = keyW[f];
        }
        if (t < 20) { s_kb[t] = keyb[t]; s_qb[t] = qb[t]; }
        __syncthreads();

        if (t < 160) {
            int pl = t / 20, a = t - (t / 20) * 20;
            float acc = s_qb[a];
            const float* qwp = qW + a;
            #pragma unroll 8
            for (int k = 0; k < 256; k++) acc += s_in[pl][k] * qwp[k * 20];
            s_q[pl][a] = acc;
        }
        __syncthreads();

        {
            int pl = t >> 5, j0 = (t & 31) * 4;
            float acc0 = 0.f, acc1 = 0.f, acc2 = 0.f, acc3 = 0.f;
            #pragma unroll
            for (int a = 0; a < 20; a++) {
                float qv = s_q[pl][a];
                acc0 += qv * s_kw[j0][a];
                acc1 += qv * s_kw[j0 + 1][a];
                acc2 += qv * s_kw[j0 + 2][a];
                acc3 += qv * s_kw[j0 + 3][a];
            }
            float4 o; o.x = acc0; o.y = acc1; o.z = acc2; o.w = acc3;
            *(float4*)(qk + (size_t)(pbase + pl) * 128 + j0) = o;

            if (t < TPV6) {
                float acc = 0.f;
                #pragma unroll
                for (int a = 0; a < 20; a++) acc += s_kb[a] * s_q[t][a];
                qoff[pbase + t] = acc;
            }
        }
    } else {
        // ---- nodes fp32 -> bf16 (round-to-nearest-even), grid-stride ----
        // 12.8M elements as 1.6M 8-float chunks; 2x float4 load -> uint4 store
        const uint64_t total8 = (uint64_t)N_NODES * 128 / 8;
        uint64_t cb = (uint64_t)(blk - 897) * 256 + t;
        const uint32_t* inb = (const uint32_t*)nodes;
        uint32_t* outb = (uint32_t*)nodes_bf;
        for (uint64_t c = cb; c < total8; c += (uint64_t)CVTBLKS * 256) {
            uint4 a = *(const uint4*)(inb + c * 8);
            uint4 b = *(const uint4*)(inb + c * 8 + 4);
            uint32_t r0 = (a.x + 0x7FFFu + ((a.x >> 16) & 1u)) >> 16;
            uint32_t r1 = (a.y + 0x7FFFu + ((a.y >> 16) & 1u)) >> 16;
            uint32_t r2 = (a.z + 0x7FFFu + ((a.z >> 16) & 1u)) >> 16;
            uint32_t r3 = (a.w + 0x7FFFu + ((a.w >> 16) & 1u)) >> 16;
            uint32_t r4 = (b.x + 0x7FFFu + ((b.x >> 16) & 1u)) >> 16;
            uint32_t r5 = (b.y + 0x7FFFu + ((b.y >> 16) & 1u)) >> 16;
            uint32_t r6 = (b.z + 0x7FFFu + ((b.z >> 16) & 1u)) >> 16;
            uint32_t r7 = (b.w + 0x7FFFu + ((b.w >> 16) & 1u)) >> 16;
            uint4 o;
            o.x = r0 | (r1 << 16);
            o.y = r2 | (r3 << 16);
            o.z = r4 | (r5 << 16);
            o.w = r6 | (r7 << 16);
            *(uint4*)(outb + c * 4) = o;
        }
    }
}

// ---------------------------------------------------------------------------
// L2: per-dst column scan over blocks (round-9/12 verified)
// ---------------------------------------------------------------------------
__global__ __launch_bounds__(256) void colscan_kernel(
    int* __restrict__ blockhist, int* __restrict__ totals)
{
    int i = blockIdx.x * 256 + threadIdx.x;
    if (i >= N_PART) return;
    int run = 0;
    for (int b = 0; b < NBLK; b++) {
        size_t idx = (size_t)b * N_PART + i;
        int v = blockhist[idx];
        blockhist[idx] = run;
        run += v;
    }
    totals[i] = run;
}

// ---------------------------------------------------------------------------
// L3: exclusive scan of totals[5000] -> offsets[5001] (verified)
// ---------------------------------------------------------------------------
__global__ __launch_bounds__(256) void scan_kernel(
    const int* __restrict__ totals, int* __restrict__ offsets)
{
    __shared__ int ss[256];
    int t = threadIdx.x;
    const int CH = 20;
    int beg = t * CH;
    int end = min(beg + CH, N_PART);
    int lsum = 0;
    for (int i = beg; i < end; i++) lsum += totals[i];
    ss[t] = lsum;
    __syncthreads();
    for (int off = 1; off < 256; off <<= 1) {
        int v = (t >= off) ? ss[t - off] : 0;
        __syncthreads();
        ss[t] += v;
        __syncthreads();
    }
    int base = ss[t] - lsum;
    for (int i = beg; i < end; i++) {
        offsets[i] = base;
        base += totals[i];
    }
    if (t == 0) offsets[N_PART] = N_EDGES;
}

// ---------------------------------------------------------------------------
// L4: scatter src into dst-sorted order using per-block LDS cursors (verified)
// ---------------------------------------------------------------------------
__global__ __launch_bounds__(256) void scatter_sorted_kernel(
    const int* __restrict__ src, const int* __restrict__ dst,
    const int* __restrict__ offsets, const int* __restrict__ blockhist,
    int* __restrict__ ssrc)
{
    __shared__ int cur[N_PART];
    int b = blockIdx.x;
    for (int i = threadIdx.x; i < N_PART; i += 256)
        cur[i] = offsets[i] + blockhist[(size_t)b * N_PART + i];
    __syncthreads();
    int beg = b * EPB, end = min(beg + EPB, N_EDGES);
    for (int e = beg + threadIdx.x; e < end; e += 256) {
        int d = dst[e];
        int pos = atomicAdd(&cur[d], 1);
        ssrc[pos] = src[e];
    }
}

// ---------------------------------------------------------------------------
// L5a: edge aggregation over bf16 node rows (256 B gathers instead of 512 B:
// halves both HBM bytes and 64B-line requests of the random gather).
// Structure identical to the verified round-0 form; x loads are uint2 (8 B)
// + bf16->f32 unpack; q/agg stay fp32.
// ---------------------------------------------------------------------------
__global__ __launch_bounds__(256) void edge_agg_bf16_kernel(
    const unsigned short* __restrict__ nodes_bf, const float* __restrict__ qk,
    const float* __restrict__ qoff,
    const int* __restrict__ offsets, const int* __restrict__ ssrc,
    float* __restrict__ agg, float* __restrict__ att_sum)
{
    const float norm = 0.22360679774997896f;  // 1/sqrt(20)
    int p = blockIdx.x;
    int tid = threadIdx.x;
    int lane = tid & 63;
    int wave = tid >> 6;
    int half = lane >> 5;
    int colq = (lane & 31) * 4;

    const float4 q = *(const float4*)(qk + (size_t)p * 128 + colq);
    float qo = qoff[p];
    int beg = offsets[p], end = offsets[p + 1];
    int n = end - beg;
    int np = (n + 1) >> 1;
    int npfull = n >> 1;

    float4 a = {0.f, 0.f, 0.f, 0.f};
    float asum = 0.f;

    int pi = wave;
    for (; pi + 12 < npfull; pi += 16) {
        int e0 = beg + 2 * pi + half;
        int s0 = ssrc[e0];
        int s1 = ssrc[e0 + 8];
        int s2 = ssrc[e0 + 16];
        int s3 = ssrc[e0 + 24];
        uint2 r0 = *(const uint2*)(nodes_bf + (size_t)s0 * 128 + colq);
        uint2 r1 = *(const uint2*)(nodes_bf + (size_t)s1 * 128 + colq);
        uint2 r2 = *(const uint2*)(nodes_bf + (size_t)s2 * 128 + colq);
        uint2 r3 = *(const uint2*)(nodes_bf + (size_t)s3 * 128 + colq);
        float4 x0 = bf4_to_f4(r0);
        float4 x1 = bf4_to_f4(r1);
        float4 x2 = bf4_to_f4(r2);
        float4 x3 = bf4_to_f4(r3);
        float d0 = x0.x * q.x + x0.y * q.y + x0.z * q.z + x0.w * q.w;
        float d1 = x1.x * q.x + x1.y * q.y + x1.z * q.z + x1.w * q.w;
        float d2 = x2.x * q.x + x2.y * q.y + x2.z * q.z + x2.w * q.w;
        float d3 = x3.x * q.x + x3.y * q.y + x3.z * q.z + x3.w * q.w;
        #pragma unroll
        for (int off = 1; off <= 16; off <<= 1) {
            d0 += __shfl_xor(d0, off, 64);
            d1 += __shfl_xor(d1, off, 64);
            d2 += __shfl_xor(d2, off, 64);
            d3 += __shfl_xor(d3, off, 64);
        }
        float t0 = (d0 + qo) * norm;
        float t1 = (d1 + qo) * norm;
        float t2 = (d2 + qo) * norm;
        float t3 = (d3 + qo) * norm;
        a.x += t0 * x0.x + t1 * x1.x + t2 * x2.x + t3 * x3.x;
        a.y += t0 * x0.y + t1 * x1.y + t2 * x2.y + t3 * x3.y;
        a.z += t0 * x0.z + t1 * x1.z + t2 * x2.z + t3 * x3.z;
        a.w += t0 * x0.w + t1 * x1.w + t2 * x2.w + t3 * x3.w;
        asum += t0 + t1 + t2 + t3;
    }
    for (; pi < np; pi += 4) {
        int e0 = beg + 2 * pi;
        bool has1 = (e0 + 1 < end);
        int s0 = ssrc[e0];
        int s1 = has1 ? ssrc[e0 + 1] : s0;
        int s = half ? s1 : s0;
        uint2 r = *(const uint2*)(nodes_bf + (size_t)s * 128 + colq);
        float4 x = bf4_to_f4(r);
        float d = x.x * q.x + x.y * q.y + x.z * q.z + x.w * q.w;
        #pragma unroll
        for (int off = 1; off <= 16; off <<= 1) d += __shfl_xor(d, off, 64);
        float att = (d + qo) * norm;
        if (half && !has1) att = 0.f;
        a.x += att * x.x; a.y += att * x.y; a.z += att * x.z; a.w += att * x.w;
        asum += att;
    }

    a.x += __shfl_xor(a.x, 32, 64);
    a.y += __shfl_xor(a.y, 32, 64);
    a.z += __shfl_xor(a.z, 32, 64);
    a.w += __shfl_xor(a.w, 32, 64);
    asum += __shfl_xor(asum, 32, 64);

    __shared__ float s_acc[4][128];
    __shared__ float s_as[4];
    if (lane < 32) {
        *(float4*)&s_acc[wave][colq] = a;
        if (lane == 0) s_as[wave] = asum;
    }
    __syncthreads();

    if (tid < 128) {
        float v = s_acc[0][tid] + s_acc[1][tid] + s_acc[2][tid] + s_acc[3][tid];
        agg[(size_t)p * 128 + tid] = v;
        if (tid == 0) att_sum[p] = s_as[0] + s_as[1] + s_as[2] + s_as[3];
    }
}

// ---------------------------------------------------------------------------
// L5b: fp32 fallback (exact round-12 verified kernel) — used when workspace
// is too small for the bf16 node table.
// ---------------------------------------------------------------------------
__global__ __launch_bounds__(256) void edge_agg_kernel(
    const float* __restrict__ nodes, const float* __restrict__ qk,
    const float* __restrict__ qoff,
    const int* __restrict__ offsets, const int* __restrict__ ssrc,
    float* __restrict__ agg, float* __restrict__ att_sum)
{
    const float norm = 0.22360679774997896f;  // 1/sqrt(20)
    int p = blockIdx.x;
    int tid = threadIdx.x;
    int lane = tid & 63;
    int wave = tid >> 6;
    int half = lane >> 5;
    int colq = (lane & 31) * 4;

    const float4 q = *(const float4*)(qk + (size_t)p * 128 + colq);
    float qo = qoff[p];
    int beg = offsets[p], end = offsets[p + 1];
    int n = end - beg;
    int np = (n + 1) >> 1;
    int npfull = n >> 1;

    float4 a = {0.f, 0.f, 0.f, 0.f};
    float asum = 0.f;

    int pi = wave;
    for (; pi + 12 < npfull; pi += 16) {
        int e0 = beg + 2 * pi + half;
        int s0 = ssrc[e0];
        int s1 = ssrc[e0 + 8];
        int s2 = ssrc[e0 + 16];
        int s3 = ssrc[e0 + 24];
        float4 x0 = *(const float4*)(nodes + (size_t)s0 * 128 + colq);
        float4 x1 = *(const float4*)(nodes + (size_t)s1 * 128 + colq);
        float4 x2 = *(const float4*)(nodes + (size_t)s2 * 128 + colq);
        float4 x3 = *(const float4*)(nodes + (size_t)s3 * 128 + colq);
        float d0 = x0.x * q.x + x0.y * q.y + x0.z * q.z + x0.w * q.w;
        float d1 = x1.x * q.x + x1.y * q.y + x1.z * q.z + x1.w * q.w;
        float d2 = x2.x * q.x + x2.y * q.y + x2.z * q.z + x2.w * q.w;
        float d3 = x3.x * q.x + x3.y * q.y + x3.z * q.z + x3.w * q.w;
        #pragma unroll
        for (int off = 1; off <= 16; off <<= 1) {
            d0 += __shfl_xor(d0, off, 64);
            d1 += __shfl_xor(d1, off, 64);
            d2 += __shfl_xor(d2, off, 64);
            d3 += __shfl_xor(d3, off, 64);
        }
        float t0 = (d0 + qo) * norm;
        float t1 = (d1 + qo) * norm;
        float t2 = (d2 + qo) * norm;
        float t3 = (d3 + qo) * norm;
        a.x += t0 * x0.x + t1 * x1.x + t2 * x2.x + t3 * x3.x;
        a.y += t0 * x0.y + t1 * x1.y + t2 * x2.y + t3 * x3.y;
        a.z += t0 * x0.z + t1 * x1.z + t2 * x2.z + t3 * x3.z;
        a.w += t0 * x0.w + t1 * x1.w + t2 * x2.w + t3 * x3.w;
        asum += t0 + t1 + t2 + t3;
    }
    for (; pi < np; pi += 4) {
        int e0 = beg + 2 * pi;
        bool has1 = (e0 + 1 < end);
        int s0 = ssrc[e0];
        int s1 = has1 ? ssrc[e0 + 1] : s0;
        int s = half ? s1 : s0;
        float4 x = *(const float4*)(nodes + (size_t)s * 128 + colq);
        float d = x.x * q.x + x.y * q.y + x.z * q.z + x.w * q.w;
        #pragma unroll
        for (int off = 1; off <= 16; off <<= 1) d += __shfl_xor(d, off, 64);
        float att = (d + qo) * norm;
        if (half && !has1) att = 0.f;
        a.x += att * x.x; a.y += att * x.y; a.z += att * x.z; a.w += att * x.w;
        asum += att;
    }

    a.x += __shfl_xor(a.x, 32, 64);
    a.y += __shfl_xor(a.y, 32, 64);
    a.z += __shfl_xor(a.z, 32, 64);
    a.w += __shfl_xor(a.w, 32, 64);
    asum += __shfl_xor(asum, 32, 64);

    __shared__ float s_acc[4][128];
    __shared__ float s_as[4];
    if (lane < 32) {
        *(float4*)&s_acc[wave][colq] = a;
        if (lane == 0) s_as[wave] = asum;
    }
    __syncthreads();

    if (tid < 128) {
        float v = s_acc[0][tid] + s_acc[1][tid] + s_acc[2][tid] + s_acc[3][tid];
        agg[(size_t)p * 128 + tid] = v;
        if (tid == 0) att_sum[p] = s_as[0] + s_as[1] + s_as[2] + s_as[3];
    }
}

// ---------------------------------------------------------------------------
// L6: K4 v6 (round-4 measured-good config) — unchanged, verified.
// ---------------------------------------------------------------------------
__global__ __launch_bounds__(256) void gru_fused_v6(
    const float* __restrict__ agg, const float* __restrict__ att_sum,
    const float* __restrict__ ph,
    const float* __restrict__ Wbig, const float* __restrict__ bvec,
    const float* __restrict__ bih, const float* __restrict__ bhh,
    const float* __restrict__ lng, const float* __restrict__ lnb,
    const float* __restrict__ W1, const float* __restrict__ b1,
    const float* __restrict__ W2, const float* __restrict__ b2,
    float* __restrict__ out)
{
    __shared__ float s_in[TPV6][256];    // [agg | h] per particle (8192 B)
    __shared__ float s_ln[TPV6][128];    //                        (4096 B)
    __shared__ float s_hid[TPV6][64];    //                        (2048 B)

    int t = threadIdx.x;
    int pbase = blockIdx.x * TPV6;

    for (int f = t; f < TPV6 * 64; f += 256) {
        int pl = f >> 6, r = f & 63;
        int c4 = r * 4;
        int p = pbase + pl;
        float4 v;
        if (c4 < 128) v = *(const float4*)(agg + (size_t)p * 128 + c4);
        else          v = *(const float4*)(ph + (size_t)p * 128 + (c4 - 128));
        *(float4*)&s_in[pl][c4] = v;
    }

    int c  = t & 127;
    int j4 = c * 4;
    int pg = t >> 7;
    float4 cb, bv;
    cb.x = bih[c]       + bhh[c];        bv.x = bvec[c];        // r
    cb.y = bih[128 + c] + bhh[128 + c];  bv.y = bvec[128 + c];  // z
    cb.z = bih[256 + c];                 bv.z = bvec[256 + c];  // i_n
    cb.w = bhh[256 + c];                 bv.w = 0.f;            // h_n
    float4 acc[4];
    #pragma unroll
    for (int i = 0; i < 4; i++) {
        float as = att_sum[pbase + pg * 4 + i];
        acc[i].x = cb.x + as * bv.x;
        acc[i].y = cb.y + as * bv.y;
        acc[i].z = cb.z + as * bv.z;
        acc[i].w = cb.w + as * bv.w;
    }
    __syncthreads();

    // ---- K-loop: barrier-free, 1-body-deep prefetch
    const float* wp = Wbig + j4;
    float4 w0 = *(const float4*)(wp);
    float4 w1 = *(const float4*)(wp + 512);
    float4 w2 = *(const float4*)(wp + 1024);
    float4 w3 = *(const float4*)(wp + 1536);
    float4 x0 = *(const float4*)&s_in[pg * 4 + 0][0];
    float4 x1 = *(const float4*)&s_in[pg * 4 + 1][0];
    float4 x2 = *(const float4*)&s_in[pg * 4 + 2][0];
    float4 x3 = *(const float4*)&s_in[pg * 4 + 3][0];
    for (int k = 0; k < 256; k += 4) {
        float4 cw0 = w0, cw1 = w1, cw2 = w2, cw3 = w3;
        float4 cx0 = x0, cx1 = x1, cx2 = x2, cx3 = x3;
        if (k < 252) {
            const float* wn = wp + (size_t)(k + 4) * 512;
            w0 = *(const float4*)(wn);
            w1 = *(const float4*)(wn + 512);
            w2 = *(const float4*)(wn + 1024);
            w3 = *(const float4*)(wn + 1536);
            x0 = *(const float4*)&s_in[pg * 4 + 0][k + 4];
            x1 = *(const float4*)&s_in[pg * 4 + 1][k + 4];
            x2 = *(const float4*)&s_in[pg * 4 + 2][k + 4];
            x3 = *(const float4*)&s_in[pg * 4 + 3][k + 4];
        }
        gru_body(acc, cw0, cw1, cw2, cw3, cx0, cx1, cx2, cx3);
    }

    // ---- gates entirely in registers: hn = (1-z)*n + z*h
    #pragma unroll
    for (int i = 0; i < 4; i++) {
        int pl = pg * 4 + i;
        float r = sigmoid_(acc[i].x);
        float z = sigmoid_(acc[i].y);
        float n = tanh_(acc[i].z + r * acc[i].w);
        float h = s_in[pl][128 + c];
        s_ln[pl][c] = (1.f - z) * n + z * h;
    }
    __syncthreads();

    // ---- LayerNorm per particle
    {
        int wv = t >> 6, l = t & 63;
        for (int pl = wv; pl < TPV6; pl += 4) {
            float v0 = s_ln[pl][l * 2], v1 = s_ln[pl][l * 2 + 1];
            float sum = v0 + v1, sq = v0 * v0 + v1 * v1;
            #pragma unroll
            for (int off = 1; off <= 32; off <<= 1) {
                sum += __shfl_xor(sum, off, 64);
                sq  += __shfl_xor(sq, off, 64);
            }
            float mu = sum * (1.f / 128.f);
            float var = sq * (1.f / 128.f) - mu * mu;
            float rstd = rsqrtf(var + 1e-5f);
            s_ln[pl][l * 2]     = (v0 - mu) * rstd * lng[l * 2] + lnb[l * 2];
            s_ln[pl][l * 2 + 1] = (v1 - mu) * rstd * lng[l * 2 + 1] + lnb[l * 2 + 1];
        }
    }
    __syncthreads();

    // ---- MLP hidden (8*64 = 512 outputs)
    for (int idx = t; idx < TPV6 * 64; idx += 256) {
        int pl = idx >> 6, u = idx & 63;
        float a0 = b1[u];
        #pragma unroll 4
        for (int k = 0; k < 128; k++) a0 += s_ln[pl][k] * W1[k * 64 + u];
        s_hid[pl][u] = fmaxf(a0, 0.f);
    }
    __syncthreads();

    // ---- MLP out + residual (256 column-quads)
    for (int idx = t; idx < TPV6 * 32; idx += 256) {
        int pl = idx >> 5, qd = idx & 31;
        int c4 = qd * 4;
        float4 o = *(const float4*)(b2 + c4);
        #pragma unroll 4
        for (int u = 0; u < 64; u++) {
            float av = s_hid[pl][u];
            float4 w = *(const float4*)(W2 + u * 128 + c4);
            o.x += av * w.x; o.y += av * w.y; o.z += av * w.z; o.w += av * w.w;
        }
        float4 h4 = *(const float4*)&s_in[pl][128 + c4];
        float4 res;
        res.x = h4.x + o.x; res.y = h4.y + o.y;
        res.z = h4.z + o.z; res.w = h4.w + o.w;
        *(float4*)(out + (size_t)(pbase + pl) * 128 + c4) = res;
    }
}

// ---------------------------------------------------------------------------
extern "C" void kernel_launch(void* const* d_in, const int* in_sizes, int n_in,
                              void* d_out, int out_size, void* d_ws, size_t ws_size,
                              hipStream_t stream) {
    const float* nodes = (const float*)d_in[0];
    const float* ph    = (const float*)d_in[1];
    const float* gr    = (const float*)d_in[2];
    const int*   src   = (const int*)d_in[3];
    const int*   dst   = (const int*)d_in[4];
    const float* keyW  = (const float*)d_in[5];
    const float* keyb  = (const float*)d_in[6];
    const float* valW  = (const float*)d_in[7];
    const float* valb  = (const float*)d_in[8];
    const float* qW    = (const float*)d_in[9];
    const float* qb    = (const float*)d_in[10];
    const float* Wih   = (const float*)d_in[11];
    const float* Whh   = (const float*)d_in[12];
    const float* bih   = (const float*)d_in[13];
    const float* bhh   = (const float*)d_in[14];
    const float* lng   = (const float*)d_in[15];
    const float* lnb   = (const float*)d_in[16];
    const float* W1    = (const float*)d_in[17];
    const float* b1    = (const float*)d_in[18];
    const float* W2    = (const float*)d_in[19];
    const float* b2    = (const float*)d_in[20];
    float* out = (float*)d_out;

    // workspace layout (4-byte words; all offsets 16B-aligned)
    float* ws_f      = (float*)d_ws;
    float* qk        = ws_f;                     // 640,000
    float* qoff      = qk + 640000;              // 5,008
    float* agg       = qoff + 5008;              // 640,000
    float* att_sum   = agg + 640000;             // 5,008
    int*   totals    = (int*)(att_sum + 5008);   // 5,008
    int*   offsets   = totals + 5008;            // 5,008
    int*   blockhist = offsets + 5008;           // NBLK*5000
    int*   ssrc      = blockhist + (size_t)NBLK * N_PART;  // 1,000,000
    float* Wbig      = (float*)(ssrc + 1000000); // 131,072
    float* bvec      = Wbig + 131072;            // 512 (384 used)
    unsigned short* nodes_bf = (unsigned short*)(bvec + 512);  // 12.8M ushorts

    // bf16 node table needs 12,286,464 + 25,600,000 B of workspace.
    int do_bf = (ws_size >= (size_t)38000000) ? 1 : 0;

    // L1: fused front (Wcomb | zero-g3 | Whh-copy | bvec | hist | query
    //     [| nodes->bf16 when workspace permits])
    fused_front_kernel<<<897 + (do_bf ? CVTBLKS : 0), 256, 0, stream>>>(
        valW, Wih, Whh, Wbig,
        valb, bvec,
        dst, blockhist,
        ph, gr, qW, qb, keyW, keyb, qk, qoff,
        nodes, nodes_bf);

    // L2: colscan (20 blocks).
    colscan_kernel<<<(N_PART + 255) / 256, 256, 0, stream>>>(blockhist, totals);

    // L3: exclusive scan (1 block).
    scan_kernel<<<1, 256, 0, stream>>>(totals, offsets);

    // L4: scatter with per-block LDS cursors (128 blocks).
    scatter_sorted_kernel<<<NBLK, 256, 0, stream>>>(src, dst, offsets, blockhist, ssrc);

    // L5: edge aggregation — bf16 gathers (half the bytes/lines) when the
    // table fits, else the verified fp32 path.
    if (do_bf)
        edge_agg_bf16_kernel<<<N_PART, 256, 0, stream>>>(nodes_bf, qk, qoff, offsets, ssrc, agg, att_sum);
    else
        edge_agg_kernel<<<N_PART, 256, 0, stream>>>(nodes, qk, qoff, offsets, ssrc, agg, att_sum);

    // L6: GRU + LN + MLP + residual (round-4 v6 config).
    gru_fused_v6<<<N_PART / TPV6, 256, 0, stream>>>(
        agg, att_sum, ph, Wbig, bvec, bih, bhh, lng, lnb, W1, b1, W2, b2, out);
}

// Round 14
// 269.329 us; speedup vs baseline: 1.1738x; 1.0240x over previous
//
#include <hip/hip_runtime.h>
#include <math.h>

#define N_NODES 100000
#define N_PART  5000
#define N_EDGES 1000000
#define D_NODE  128
#define D_PART  128
#define D_ATT   20
#define NBLK    128   // counting-sort blocks
#define EPB     ((N_EDGES + NBLK - 1) / NBLK)
#define TPV6    8     // particles per block in gru_fused_v6 / query path
#define QBLKS   (N_PART / TPV6)   // 625 query blocks
#define CVTBLKS 1024  // nodes->bf16 conversion blocks

__device__ __forceinline__ float sigmoid_(float x) { return 1.f / (1.f + __expf(-x)); }
__device__ __forceinline__ float tanh_(float x)    { return 1.f - 2.f / (__expf(2.f * x) + 1.f); }

// 4 bf16 (packed in uint2, ushort order [e0,e1,e2,e3]) -> float4
__device__ __forceinline__ float4 bf4_to_f4(uint2 r) {
    float4 f;
    f.x = __uint_as_float(r.x << 16);
    f.y = __uint_as_float(r.x & 0xFFFF0000u);
    f.z = __uint_as_float(r.y << 16);
    f.w = __uint_as_float(r.y & 0xFFFF0000u);
    return f;
}

// fp32 -> bf16 (round-to-nearest-even), returns low 16 bits
__device__ __forceinline__ unsigned short f_to_bf(float v) {
    uint32_t u = __float_as_uint(v);
    return (unsigned short)((u + 0x7FFFu + ((u >> 16) & 1u)) >> 16);
}

// 16-FMA body for the 512-wide GRU GEMM (4 k-rows x 4 cols x 4 particles)
__device__ __forceinline__ void gru_body(float4 acc[4],
    float4 w0, float4 w1, float4 w2, float4 w3,
    float4 x0, float4 x1, float4 x2, float4 x3)
{
    acc[0].x += x0.x * w0.x + x0.y * w1.x + x0.z * w2.x + x0.w * w3.x;
    acc[0].y += x0.x * w0.y + x0.y * w1.y + x0.z * w2.y + x0.w * w3.y;
    acc[0].z += x0.x * w0.z + x0.y * w1.z + x0.z * w2.z + x0.w * w3.z;
    acc[0].w += x0.x * w0.w + x0.y * w1.w + x0.z * w2.w + x0.w * w3.w;
    acc[1].x += x1.x * w0.x + x1.y * w1.x + x1.z * w2.x + x1.w * w3.x;
    acc[1].y += x1.x * w0.y + x1.y * w1.y + x1.z * w2.y + x1.w * w3.y;
    acc[1].z += x1.x * w0.z + x1.y * w1.z + x1.z * w2.z + x1.w * w3.z;
    acc[1].w += x1.x * w0.w + x1.y * w1.w + x1.z * w2.w + x1.w * w3.w;
    acc[2].x += x2.x * w0.x + x2.y * w1.x + x2.z * w2.x + x2.w * w3.x;
    acc[2].y += x2.x * w0.y + x2.y * w1.y + x2.z * w2.y + x2.w * w3.y;
    acc[2].z += x2.x * w0.z + x2.y * w1.z + x2.z * w2.z + x2.w * w3.z;
    acc[2].w += x2.x * w0.w + x2.y * w1.w + x2.z * w2.w + x2.w * w3.w;
    acc[3].x += x3.x * w0.x + x3.y * w1.x + x3.z * w2.x + x3.w * w3.x;
    acc[3].y += x3.x * w0.y + x3.y * w1.y + x3.z * w2.y + x3.w * w3.y;
    acc[3].z += x3.x * w0.z + x3.y * w1.z + x3.z * w2.z + x3.w * w3.z;
    acc[3].w += x3.x * w0.w + x3.y * w1.w + x3.z * w2.w + x3.w * w3.w;
}

// packed-Wbig ushort index for (row k, interleaved col jn):
//   uint4 cell (k>>1, jn>>2); within cell: (k&1)*4 + (jn&3)
__device__ __forceinline__ size_t wpk_idx(int k, int jn) {
    return ((size_t)(k >> 1) * 128 + (jn >> 2)) * 8 + ((k & 1) << 2) + (jn & 3);
}

// ---------------------------------------------------------------------------
// L1 — fused front-end (897 or 1921 blocks). Disjoint sections:
//   [0,12):    Wcomb tiled GEMM -> bf16 packed Wpack (rows 0-127, g<3)
//   [12,14):   zero-fill Wpack rows 0-127, gate g=3
//   [14,142):  copy Whh into Wpack rows 128-255 (bf16), 2 entries/thread
//   [142,144): bvec (fp32)
//   [144,272): block_hist -> blockhist (verified)
//   [272,897): query two-stage rank-20 (verified)
//   [897,1921): nodes fp32 -> bf16 (verified round 13)
// ---------------------------------------------------------------------------
__global__ __launch_bounds__(256) void fused_front_kernel(
    const float* __restrict__ valW, const float* __restrict__ Wih,
    const float* __restrict__ Whh, unsigned short* __restrict__ Wpack,
    const float* __restrict__ valb, float* __restrict__ bvec,
    const int* __restrict__ dst, int* __restrict__ blockhist,
    const float* __restrict__ ph, const float* __restrict__ gr,
    const float* __restrict__ qW, const float* __restrict__ qb,
    const float* __restrict__ keyW, const float* __restrict__ keyb,
    float* __restrict__ qk, float* __restrict__ qoff,
    const float* __restrict__ nodes, unsigned short* __restrict__ nodes_bf)
{
    __shared__ float pool[5000];   // 20000 B unioned
    int blk = blockIdx.x;
    int t = threadIdx.x;

    if (blk < 12) {
        // ---- Wcomb tiled GEMM: C = valW(128x128) * Wih(384x128)^T ----
        float (*sA)[33] = (float (*)[33])pool;          // 64x33
        float (*sB)[33] = (float (*)[33])(pool + 2112); // 64x33
        int bk = blk / 6, bj = blk - bk * 6;
        int k0 = bk * 64, j0 = bj * 64;
        int tk = t >> 4, tj = t & 15;
        float acc[4][4];
        #pragma unroll
        for (int i = 0; i < 4; i++)
            #pragma unroll
            for (int j = 0; j < 4; j++) acc[i][j] = 0.f;

        for (int mc = 0; mc < 128; mc += 32) {
            #pragma unroll
            for (int s = 0; s < 2; s++) {
                int f = t + s * 256;          // 0..511
                int r = f >> 3, c4 = (f & 7) * 4;
                *(float4*)&sA[r][c4] = *(const float4*)(valW + (size_t)(k0 + r) * 128 + mc + c4);
                *(float4*)&sB[r][c4] = *(const float4*)(Wih  + (size_t)(j0 + r) * 128 + mc + c4);
            }
            __syncthreads();
            #pragma unroll 8
            for (int mm = 0; mm < 32; mm++) {
                float a0 = sA[tk * 4 + 0][mm], a1 = sA[tk * 4 + 1][mm];
                float a2 = sA[tk * 4 + 2][mm], a3 = sA[tk * 4 + 3][mm];
                float b0 = sB[tj * 4 + 0][mm], b1 = sB[tj * 4 + 1][mm];
                float b2 = sB[tj * 4 + 2][mm], b3 = sB[tj * 4 + 3][mm];
                acc[0][0] += a0 * b0; acc[0][1] += a0 * b1; acc[0][2] += a0 * b2; acc[0][3] += a0 * b3;
                acc[1][0] += a1 * b0; acc[1][1] += a1 * b1; acc[1][2] += a1 * b2; acc[1][3] += a1 * b3;
                acc[2][0] += a2 * b0; acc[2][1] += a2 * b1; acc[2][2] += a2 * b2; acc[2][3] += a2 * b3;
                acc[3][0] += a3 * b0; acc[3][1] += a3 * b1; acc[3][2] += a3 * b2; acc[3][3] += a3 * b3;
            }
            __syncthreads();
        }
        // write-out bf16-packed with gate-interleave: jn = (oj&127)*4 + (oj>>7)
        #pragma unroll
        for (int i = 0; i < 4; i++) {
            int k = k0 + tk * 4 + i;
            #pragma unroll
            for (int j = 0; j < 4; j++) {
                int oj = j0 + tj * 4 + j;            // < 384
                int jn = (oj & 127) * 4 + (oj >> 7);
                Wpack[wpk_idx(k, jn)] = f_to_bf(acc[i][j]);
            }
        }
    } else if (blk < 14) {
        // ---- zero-fill rows 0-127, g=3 ----
        for (int f = t; f < 8192; f += 256) {
            int e = (blk - 12) * 8192 + f;   // 0..16383
            int k = e >> 7, c = e & 127;
            Wpack[wpk_idx(k, c * 4 + 3)] = 0;
        }
    } else if (blk < 142) {
        // ---- copy Whh rows 128-255 (2 entries per thread, bf16) ----
        #pragma unroll
        for (int s = 0; s < 2; s++) {
            int idx = 65536 + (blk - 14) * 512 + s * 256 + t;  // 65536..131071
            int k = idx >> 9;            // 128..255
            int jn = idx & 511;
            int j = (jn & 3) * 128 + (jn >> 2);
            int kp = k - 128;
            float v = 0.f;
            if (j < 256)       v = Whh[j * 128 + kp];
            else if (j >= 384) v = Whh[(j - 128) * 128 + kp];
            Wpack[wpk_idx(k, jn)] = f_to_bf(v);
        }
    } else if (blk < 144) {
        // ---- bvec (verified) ----
        int c = (blk - 142) * 256 + t;
        if (c < 384) {
            float acc = 0.f;
            #pragma unroll 8
            for (int m = 0; m < 128; m++) acc += valb[m] * Wih[c * 128 + m];
            bvec[c] = acc;
        }
    } else if (blk < 272) {
        // ---- block_hist -> blockhist (verified) ----
        int b = blk - 144;
        int* h = (int*)pool;
        for (int i = t; i < N_PART; i += 256) h[i] = 0;
        __syncthreads();
        int beg = b * EPB, end = min(beg + EPB, N_EDGES);
        for (int e = beg + t; e < end; e += 256)
            atomicAdd(&h[dst[e]], 1);
        __syncthreads();
        for (int i = t; i < N_PART; i += 256)
            blockhist[(size_t)b * N_PART + i] = h[i];
    } else if (blk < 897) {
        // ---- query two-stage (rank-20, LDS-resident — verified) ----
        float (*s_in)[260] = (float (*)[260])pool;
        float (*s_q)[20]   = (float (*)[20])(pool + 2080);
        float (*s_kw)[21]  = (float (*)[21])(pool + 2240);
        float* s_kb = pool + 4928;
        float* s_qb = pool + 4948;

        int pbase = (blk - 272) * TPV6;

        for (int f = t; f < TPV6 * 64; f += 256) {
            int pl = f >> 6, r = f & 63;
            int c4 = r * 4;
            int p = pbase + pl;
            float4 v;
            if (c4 < 128) v = *(const float4*)(ph + (size_t)p * 128 + c4);
            else          v = *(const float4*)(gr + (size_t)p * 128 + (c4 - 128));
            *(float4*)&s_in[pl][c4] = v;
        }
        for (int f = t; f < 2560; f += 256) {
            int j = f / 20, a = f - j * 20;
            s_kw[j][a] = keyW[f];
        }
        if (t < 20) { s_kb[t] = keyb[t]; s_qb[t] = qb[t]; }
        __syncthreads();

        if (t < 160) {
            int pl = t / 20, a = t - (t / 20) * 20;
            float acc = s_qb[a];
            const float* qwp = qW + a;
            #pragma unroll 8
            for (int k = 0; k < 256; k++) acc += s_in[pl][k] * qwp[k * 20];
            s_q[pl][a] = acc;
        }
        __syncthreads();

        {
            int pl = t >> 5, j0 = (t & 31) * 4;
            float acc0 = 0.f, acc1 = 0.f, acc2 = 0.f, acc3 = 0.f;
            #pragma unroll
            for (int a = 0; a < 20; a++) {
                float qv = s_q[pl][a];
                acc0 += qv * s_kw[j0][a];
                acc1 += qv * s_kw[j0 + 1][a];
                acc2 += qv * s_kw[j0 + 2][a];
                acc3 += qv * s_kw[j0 + 3][a];
            }
            float4 o; o.x = acc0; o.y = acc1; o.z = acc2; o.w = acc3;
            *(float4*)(qk + (size_t)(pbase + pl) * 128 + j0) = o;

            if (t < TPV6) {
                float acc = 0.f;
                #pragma unroll
                for (int a = 0; a < 20; a++) acc += s_kb[a] * s_q[t][a];
                qoff[pbase + t] = acc;
            }
        }
    } else {
        // ---- nodes fp32 -> bf16 (RNE), grid-stride (verified round 13) ----
        const uint64_t total8 = (uint64_t)N_NODES * 128 / 8;
        uint64_t cb = (uint64_t)(blk - 897) * 256 + t;
        const uint32_t* inb = (const uint32_t*)nodes;
        uint32_t* outb = (uint32_t*)nodes_bf;
        for (uint64_t c = cb; c < total8; c += (uint64_t)CVTBLKS * 256) {
            uint4 a = *(const uint4*)(inb + c * 8);
            uint4 b = *(const uint4*)(inb + c * 8 + 4);
            uint32_t r0 = (a.x + 0x7FFFu + ((a.x >> 16) & 1u)) >> 16;
            uint32_t r1 = (a.y + 0x7FFFu + ((a.y >> 16) & 1u)) >> 16;
            uint32_t r2 = (a.z + 0x7FFFu + ((a.z >> 16) & 1u)) >> 16;
            uint32_t r3 = (a.w + 0x7FFFu + ((a.w >> 16) & 1u)) >> 16;
            uint32_t r4 = (b.x + 0x7FFFu + ((b.x >> 16) & 1u)) >> 16;
            uint32_t r5 = (b.y + 0x7FFFu + ((b.y >> 16) & 1u)) >> 16;
            uint32_t r6 = (b.z + 0x7FFFu + ((b.z >> 16) & 1u)) >> 16;
            uint32_t r7 = (b.w + 0x7FFFu + ((b.w >> 16) & 1u)) >> 16;
            uint4 o;
            o.x = r0 | (r1 << 16);
            o.y = r2 | (r3 << 16);
            o.z = r4 | (r5 << 16);
            o.w = r6 | (r7 << 16);
            *(uint4*)(outb + c * 4) = o;
        }
    }
}

// ---------------------------------------------------------------------------
// L2: per-dst column scan over blocks (verified)
// ---------------------------------------------------------------------------
__global__ __launch_bounds__(256) void colscan_kernel(
    int* __restrict__ blockhist, int* __restrict__ totals)
{
    int i = blockIdx.x * 256 + threadIdx.x;
    if (i >= N_PART) return;
    int run = 0;
    for (int b = 0; b < NBLK; b++) {
        size_t idx = (size_t)b * N_PART + i;
        int v = blockhist[idx];
        blockhist[idx] = run;
        run += v;
    }
    totals[i] = run;
}

// ---------------------------------------------------------------------------
// L3: exclusive scan of totals[5000] -> offsets[5001] (verified)
// ---------------------------------------------------------------------------
__global__ __launch_bounds__(256) void scan_kernel(
    const int* __restrict__ totals, int* __restrict__ offsets)
{
    __shared__ int ss[256];
    int t = threadIdx.x;
    const int CH = 20;
    int beg = t * CH;
    int end = min(beg + CH, N_PART);
    int lsum = 0;
    for (int i = beg; i < end; i++) lsum += totals[i];
    ss[t] = lsum;
    __syncthreads();
    for (int off = 1; off < 256; off <<= 1) {
        int v = (t >= off) ? ss[t - off] : 0;
        __syncthreads();
        ss[t] += v;
        __syncthreads();
    }
    int base = ss[t] - lsum;
    for (int i = beg; i < end; i++) {
        offsets[i] = base;
        base += totals[i];
    }
    if (t == 0) offsets[N_PART] = N_EDGES;
}

// ---------------------------------------------------------------------------
// L4: scatter src into dst-sorted order using per-block LDS cursors (verified)
// ---------------------------------------------------------------------------
__global__ __launch_bounds__(256) void scatter_sorted_kernel(
    const int* __restrict__ src, const int* __restrict__ dst,
    const int* __restrict__ offsets, const int* __restrict__ blockhist,
    int* __restrict__ ssrc)
{
    __shared__ int cur[N_PART];
    int b = blockIdx.x;
    for (int i = threadIdx.x; i < N_PART; i += 256)
        cur[i] = offsets[i] + blockhist[(size_t)b * N_PART + i];
    __syncthreads();
    int beg = b * EPB, end = min(beg + EPB, N_EDGES);
    for (int e = beg + threadIdx.x; e < end; e += 256) {
        int d = dst[e];
        int pos = atomicAdd(&cur[d], 1);
        ssrc[pos] = src[e];
    }
}

// ---------------------------------------------------------------------------
// L5a: edge aggregation over bf16 node rows (verified round 13: 72 -> <50us)
// ---------------------------------------------------------------------------
__global__ __launch_bounds__(256) void edge_agg_bf16_kernel(
    const unsigned short* __restrict__ nodes_bf, const float* __restrict__ qk,
    const float* __restrict__ qoff,
    const int* __restrict__ offsets, const int* __restrict__ ssrc,
    float* __restrict__ agg, float* __restrict__ att_sum)
{
    const float norm = 0.22360679774997896f;  // 1/sqrt(20)
    int p = blockIdx.x;
    int tid = threadIdx.x;
    int lane = tid & 63;
    int wave = tid >> 6;
    int half = lane >> 5;
    int colq = (lane & 31) * 4;

    const float4 q = *(const float4*)(qk + (size_t)p * 128 + colq);
    float qo = qoff[p];
    int beg = offsets[p], end = offsets[p + 1];
    int n = end - beg;
    int np = (n + 1) >> 1;
    int npfull = n >> 1;

    float4 a = {0.f, 0.f, 0.f, 0.f};
    float asum = 0.f;

    int pi = wave;
    for (; pi + 12 < npfull; pi += 16) {
        int e0 = beg + 2 * pi + half;
        int s0 = ssrc[e0];
        int s1 = ssrc[e0 + 8];
        int s2 = ssrc[e0 + 16];
        int s3 = ssrc[e0 + 24];
        uint2 r0 = *(const uint2*)(nodes_bf + (size_t)s0 * 128 + colq);
        uint2 r1 = *(const uint2*)(nodes_bf + (size_t)s1 * 128 + colq);
        uint2 r2 = *(const uint2*)(nodes_bf + (size_t)s2 * 128 + colq);
        uint2 r3 = *(const uint2*)(nodes_bf + (size_t)s3 * 128 + colq);
        float4 x0 = bf4_to_f4(r0);
        float4 x1 = bf4_to_f4(r1);
        float4 x2 = bf4_to_f4(r2);
        float4 x3 = bf4_to_f4(r3);
        float d0 = x0.x * q.x + x0.y * q.y + x0.z * q.z + x0.w * q.w;
        float d1 = x1.x * q.x + x1.y * q.y + x1.z * q.z + x1.w * q.w;
        float d2 = x2.x * q.x + x2.y * q.y + x2.z * q.z + x2.w * q.w;
        float d3 = x3.x * q.x + x3.y * q.y + x3.z * q.z + x3.w * q.w;
        #pragma unroll
        for (int off = 1; off <= 16; off <<= 1) {
            d0 += __shfl_xor(d0, off, 64);
            d1 += __shfl_xor(d1, off, 64);
            d2 += __shfl_xor(d2, off, 64);
            d3 += __shfl_xor(d3, off, 64);
        }
        float t0 = (d0 + qo) * norm;
        float t1 = (d1 + qo) * norm;
        float t2 = (d2 + qo) * norm;
        float t3 = (d3 + qo) * norm;
        a.x += t0 * x0.x + t1 * x1.x + t2 * x2.x + t3 * x3.x;
        a.y += t0 * x0.y + t1 * x1.y + t2 * x2.y + t3 * x3.y;
        a.z += t0 * x0.z + t1 * x1.z + t2 * x2.z + t3 * x3.z;
        a.w += t0 * x0.w + t1 * x1.w + t2 * x2.w + t3 * x3.w;
        asum += t0 + t1 + t2 + t3;
    }
    for (; pi < np; pi += 4) {
        int e0 = beg + 2 * pi;
        bool has1 = (e0 + 1 < end);
        int s0 = ssrc[e0];
        int s1 = has1 ? ssrc[e0 + 1] : s0;
        int s = half ? s1 : s0;
        uint2 r = *(const uint2*)(nodes_bf + (size_t)s * 128 + colq);
        float4 x = bf4_to_f4(r);
        float d = x.x * q.x + x.y * q.y + x.z * q.z + x.w * q.w;
        #pragma unroll
        for (int off = 1; off <= 16; off <<= 1) d += __shfl_xor(d, off, 64);
        float att = (d + qo) * norm;
        if (half && !has1) att = 0.f;
        a.x += att * x.x; a.y += att * x.y; a.z += att * x.z; a.w += att * x.w;
        asum += att;
    }

    a.x += __shfl_xor(a.x, 32, 64);
    a.y += __shfl_xor(a.y, 32, 64);
    a.z += __shfl_xor(a.z, 32, 64);
    a.w += __shfl_xor(a.w, 32, 64);
    asum += __shfl_xor(asum, 32, 64);

    __shared__ float s_acc[4][128];
    __shared__ float s_as[4];
    if (lane < 32) {
        *(float4*)&s_acc[wave][colq] = a;
        if (lane == 0) s_as[wave] = asum;
    }
    __syncthreads();

    if (tid < 128) {
        float v = s_acc[0][tid] + s_acc[1][tid] + s_acc[2][tid] + s_acc[3][tid];
        agg[(size_t)p * 128 + tid] = v;
        if (tid == 0) att_sum[p] = s_as[0] + s_as[1] + s_as[2] + s_as[3];
    }
}

// ---------------------------------------------------------------------------
// L6: K4 v8: GEMM over bf16 ROW-PAIR-PACKED Wpack — 2 uint4 loads per 4-row
// body (was 4 float4): halves w load-issue count AND L2 bytes. 1-deep
// prefetch retained (single-variable change vs verified v6).
// ---------------------------------------------------------------------------
__global__ __launch_bounds__(256) void gru_fused_v8(
    const float* __restrict__ agg, const float* __restrict__ att_sum,
    const float* __restrict__ ph,
    const unsigned short* __restrict__ Wpack, const float* __restrict__ bvec,
    const float* __restrict__ bih, const float* __restrict__ bhh,
    const float* __restrict__ lng, const float* __restrict__ lnb,
    const float* __restrict__ W1, const float* __restrict__ b1,
    const float* __restrict__ W2, const float* __restrict__ b2,
    float* __restrict__ out)
{
    __shared__ float s_in[TPV6][256];    // [agg | h] per particle (8192 B)
    __shared__ float s_ln[TPV6][128];    //                        (4096 B)
    __shared__ float s_hid[TPV6][64];    //                        (2048 B)

    int t = threadIdx.x;
    int pbase = blockIdx.x * TPV6;

    for (int f = t; f < TPV6 * 64; f += 256) {
        int pl = f >> 6, r = f & 63;
        int c4 = r * 4;
        int p = pbase + pl;
        float4 v;
        if (c4 < 128) v = *(const float4*)(agg + (size_t)p * 128 + c4);
        else          v = *(const float4*)(ph + (size_t)p * 128 + (c4 - 128));
        *(float4*)&s_in[pl][c4] = v;
    }

    int c  = t & 127;        // output column 0..127 == column-quad index
    int pg = t >> 7;         // particle group 0/1 -> particles pg*4 .. pg*4+3
    float4 cb, bv;
    cb.x = bih[c]       + bhh[c];        bv.x = bvec[c];        // r
    cb.y = bih[128 + c] + bhh[128 + c];  bv.y = bvec[128 + c];  // z
    cb.z = bih[256 + c];                 bv.z = bvec[256 + c];  // i_n
    cb.w = bhh[256 + c];                 bv.w = 0.f;            // h_n
    float4 acc[4];
    #pragma unroll
    for (int i = 0; i < 4; i++) {
        float as = att_sum[pbase + pg * 4 + i];
        acc[i].x = cb.x + as * bv.x;
        acc[i].y = cb.y + as * bv.y;
        acc[i].z = cb.z + as * bv.z;
        acc[i].w = cb.w + as * bv.w;
    }
    __syncthreads();

    // ---- K-loop: barrier-free, 1-deep prefetch, packed bf16 w.
    // cell (k2 = k/2, c) holds rows {2k2, 2k2+1} cols {4c..4c+3}.
    const uint4* wpk = (const uint4*)Wpack;   // [k2*128 + c]
    uint4 wu = wpk[c];               // rows 0,1
    uint4 wv = wpk[128 + c];         // rows 2,3
    float4 x0 = *(const float4*)&s_in[pg * 4 + 0][0];
    float4 x1 = *(const float4*)&s_in[pg * 4 + 1][0];
    float4 x2 = *(const float4*)&s_in[pg * 4 + 2][0];
    float4 x3 = *(const float4*)&s_in[pg * 4 + 3][0];
    for (int k = 0; k < 256; k += 4) {
        uint4 cu = wu, cv = wv;
        float4 cx0 = x0, cx1 = x1, cx2 = x2, cx3 = x3;
        if (k < 252) {
            int k2n = (k >> 1) + 2;
            wu = wpk[(size_t)k2n * 128 + c];
            wv = wpk[(size_t)(k2n + 1) * 128 + c];
            x0 = *(const float4*)&s_in[pg * 4 + 0][k + 4];
            x1 = *(const float4*)&s_in[pg * 4 + 1][k + 4];
            x2 = *(const float4*)&s_in[pg * 4 + 2][k + 4];
            x3 = *(const float4*)&s_in[pg * 4 + 3][k + 4];
        }
        float4 w0 = bf4_to_f4(make_uint2(cu.x, cu.y));
        float4 w1 = bf4_to_f4(make_uint2(cu.z, cu.w));
        float4 w2 = bf4_to_f4(make_uint2(cv.x, cv.y));
        float4 w3 = bf4_to_f4(make_uint2(cv.z, cv.w));
        gru_body(acc, w0, w1, w2, w3, cx0, cx1, cx2, cx3);
    }

    // ---- gates entirely in registers: hn = (1-z)*n + z*h
    #pragma unroll
    for (int i = 0; i < 4; i++) {
        int pl = pg * 4 + i;
        float r = sigmoid_(acc[i].x);
        float z = sigmoid_(acc[i].y);
        float n = tanh_(acc[i].z + r * acc[i].w);
        float h = s_in[pl][128 + c];
        s_ln[pl][c] = (1.f - z) * n + z * h;
    }
    __syncthreads();

    // ---- LayerNorm per particle
    {
        int wv2 = t >> 6, l = t & 63;
        for (int pl = wv2; pl < TPV6; pl += 4) {
            float v0 = s_ln[pl][l * 2], v1 = s_ln[pl][l * 2 + 1];
            float sum = v0 + v1, sq = v0 * v0 + v1 * v1;
            #pragma unroll
            for (int off = 1; off <= 32; off <<= 1) {
                sum += __shfl_xor(sum, off, 64);
                sq  += __shfl_xor(sq, off, 64);
            }
            float mu = sum * (1.f / 128.f);
            float var = sq * (1.f / 128.f) - mu * mu;
            float rstd = rsqrtf(var + 1e-5f);
            s_ln[pl][l * 2]     = (v0 - mu) * rstd * lng[l * 2] + lnb[l * 2];
            s_ln[pl][l * 2 + 1] = (v1 - mu) * rstd * lng[l * 2 + 1] + lnb[l * 2 + 1];
        }
    }
    __syncthreads();

    // ---- MLP hidden (8*64 = 512 outputs)
    for (int idx = t; idx < TPV6 * 64; idx += 256) {
        int pl = idx >> 6, u = idx & 63;
        float a0 = b1[u];
        #pragma unroll 4
        for (int k = 0; k < 128; k++) a0 += s_ln[pl][k] * W1[k * 64 + u];
        s_hid[pl][u] = fmaxf(a0, 0.f);
    }
    __syncthreads();

    // ---- MLP out + residual (256 column-quads)
    for (int idx = t; idx < TPV6 * 32; idx += 256) {
        int pl = idx >> 5, qd = idx & 31;
        int c4 = qd * 4;
        float4 o = *(const float4*)(b2 + c4);
        #pragma unroll 4
        for (int u = 0; u < 64; u++) {
            float av = s_hid[pl][u];
            float4 w = *(const float4*)(W2 + u * 128 + c4);
            o.x += av * w.x; o.y += av * w.y; o.z += av * w.z; o.w += av * w.w;
        }
        float4 h4 = *(const float4*)&s_in[pl][128 + c4];
        float4 res;
        res.x = h4.x + o.x; res.y = h4.y + o.y;
        res.z = h4.z + o.z; res.w = h4.w + o.w;
        *(float4*)(out + (size_t)(pbase + pl) * 128 + c4) = res;
    }
}

// ---------------------------------------------------------------------------
extern "C" void kernel_launch(void* const* d_in, const int* in_sizes, int n_in,
                              void* d_out, int out_size, void* d_ws, size_t ws_size,
                              hipStream_t stream) {
    const float* nodes = (const float*)d_in[0];
    const float* ph    = (const float*)d_in[1];
    const float* gr    = (const float*)d_in[2];
    const int*   src   = (const int*)d_in[3];
    const int*   dst   = (const int*)d_in[4];
    const float* keyW  = (const float*)d_in[5];
    const float* keyb  = (const float*)d_in[6];
    const float* valW  = (const float*)d_in[7];
    const float* valb  = (const float*)d_in[8];
    const float* qW    = (const float*)d_in[9];
    const float* qb    = (const float*)d_in[10];
    const float* Wih   = (const float*)d_in[11];
    const float* Whh   = (const float*)d_in[12];
    const float* bih   = (const float*)d_in[13];
    const float* bhh   = (const float*)d_in[14];
    const float* lng   = (const float*)d_in[15];
    const float* lnb   = (const float*)d_in[16];
    const float* W1    = (const float*)d_in[17];
    const float* b1    = (const float*)d_in[18];
    const float* W2    = (const float*)d_in[19];
    const float* b2    = (const float*)d_in[20];
    float* out = (float*)d_out;

    // workspace layout (4-byte words; all offsets 16B-aligned)
    float* ws_f      = (float*)d_ws;
    float* qk        = ws_f;                     // 640,000
    float* qoff      = qk + 640000;              // 5,008
    float* agg       = qoff + 5008;              // 640,000
    float* att_sum   = agg + 640000;             // 5,008
    int*   totals    = (int*)(att_sum + 5008);   // 5,008
    int*   offsets   = totals + 5008;            // 5,008
    int*   blockhist = offsets + 5008;           // NBLK*5000
    int*   ssrc      = blockhist + (size_t)NBLK * N_PART;  // 1,000,000
    unsigned short* Wpack = (unsigned short*)(ssrc + 1000000); // 131,072 ushorts (256KB)
    float* bvec      = (float*)(Wpack + 131072); // 512 (384 used)
    unsigned short* nodes_bf = (unsigned short*)(bvec + 512);  // 12.8M ushorts

    // L1: fused front (Wcomb->bf16pack | zero-g3 | Whh-copy | bvec | hist |
    //     query | nodes->bf16)
    fused_front_kernel<<<897 + CVTBLKS, 256, 0, stream>>>(
        valW, Wih, Whh, Wpack,
        valb, bvec,
        dst, blockhist,
        ph, gr, qW, qb, keyW, keyb, qk, qoff,
        nodes, nodes_bf);

    // L2: colscan (20 blocks).
    colscan_kernel<<<(N_PART + 255) / 256, 256, 0, stream>>>(blockhist, totals);

    // L3: exclusive scan (1 block).
    scan_kernel<<<1, 256, 0, stream>>>(totals, offsets);

    // L4: scatter with per-block LDS cursors (128 blocks).
    scatter_sorted_kernel<<<NBLK, 256, 0, stream>>>(src, dst, offsets, blockhist, ssrc);

    // L5: edge aggregation over bf16 node rows (verified round 13).
    edge_agg_bf16_kernel<<<N_PART, 256, 0, stream>>>(nodes_bf, qk, qoff, offsets, ssrc, agg, att_sum);

    // L6: GRU + LN + MLP + residual over packed bf16 weights.
    gru_fused_v8<<<N_PART / TPV6, 256, 0, stream>>>(
        agg, att_sum, ph, Wpack, bvec, bih, bhh, lng, lnb, W1, b1, W2, b2, out);
}